// Round 5
// baseline (15086.519 us; speedup 1.0000x reference)
//
#include <hip/hip_runtime.h>
#include <hip/hip_bf16.h>
#include <cstddef>

#define N_NODES 50000
#define E_EDGES 300000
#define D 256

typedef unsigned short u16;

__device__ __forceinline__ float b2f(u16 u) {
    return __uint_as_float(((unsigned)u) << 16);
}
__device__ __forceinline__ u16 f2b(float f) {
    __hip_bfloat16 h = __float2bfloat16(f);
    return *reinterpret_cast<u16*>(&h);
}

// ---------------------------------------------------------------------------
// prep (f32 weights used in-place elsewhere; only r,z rows need repacking):
//   Wrz[j][k] = k<256 ? W_ih[j][k] : W_hh[j][k-256]    (512 x 512)
//   brz[j]    = b_ih[j] + b_hh[j]                      (512)
// ---------------------------------------------------------------------------
__global__ __launch_bounds__(256) void prep_kernel(
    const float* __restrict__ W_ih, const float* __restrict__ W_hh,
    const float* __restrict__ b_ih, const float* __restrict__ b_hh,
    float* __restrict__ Wrz, float* __restrict__ brz)
{
    int t = blockIdx.x * 256 + threadIdx.x;     // [0, 262144)
    int j = t >> 9;
    int k = t & 511;
    Wrz[t] = (k < 256) ? W_ih[j * 256 + k] : W_hh[j * 256 + (k - 256)];
    if (t < 512) brz[t] = b_ih[t] + b_hh[t];
}

// ---------------------------------------------------------------------------
// degrees per etype (launch-invariant across steps)
// ---------------------------------------------------------------------------
__global__ __launch_bounds__(256) void deg_kernel(
    const int* __restrict__ d0, const int* __restrict__ d1,
    const int* __restrict__ d2, const int* __restrict__ d3,
    float* __restrict__ deg)
{
    int i = blockIdx.x * 256 + threadIdx.x;
    if (i >= 4 * E_EDGES) return;
    int e = i / E_EDGES;
    int k = i - e * E_EDGES;
    const int* dp = (e == 0) ? d0 : (e == 1) ? d1 : (e == 2) ? d2 : d3;
    atomicAdd(&deg[e * N_NODES + dp[k]], 1.0f);
}

// ---------------------------------------------------------------------------
// scatter one etype: Hsum[dst, :] += h[src, :]  (one wave per edge)
// HBF: h is bf16 (internal state); else f32 (input x or d_out state)
// grid = E/4 = 75000 blocks exactly
// ---------------------------------------------------------------------------
template <bool HBF>
__global__ __launch_bounds__(256) void scatter_kernel(
    const void* __restrict__ hv, const int* __restrict__ sp,
    const int* __restrict__ dp, float* __restrict__ Hsum)
{
    int gt = blockIdx.x * 256 + threadIdx.x;
    int w = gt >> 6;                 // edge id, < E exactly
    int lane = threadIdx.x & 63;
    int src = sp[w];
    int dst = dp[w];
    float4 v;
    if (HBF) {
        const u16* h = (const u16*)hv;
        ushort4 u = *reinterpret_cast<const ushort4*>(h + (size_t)src * D + lane * 4);
        v = make_float4(b2f(u.x), b2f(u.y), b2f(u.z), b2f(u.w));
    } else {
        const float* h = (const float*)hv;
        v = *reinterpret_cast<const float4*>(h + (size_t)src * D + lane * 4);
    }
    float* o = Hsum + (size_t)dst * D + lane * 4;
    atomicAdd(o + 0, v.x);
    atomicAdd(o + 1, v.y);
    atomicAdd(o + 2, v.z);
    atomicAdd(o + 3, v.w);
}

// ---------------------------------------------------------------------------
// C[M,Ncol](bf16) = op(A)[M,K] @ B[Ncol,K]^T + bias  (+ C if ACCUM)
// AKIND 0: A0 f32, row-scaled by 1/max(dege[row],1)   (Hsum path)
// AKIND 1: A0 bf16, lda=K
// AKIND 2: dual: cols [0,256) bf16 A0, [256,512) bf16 A1  (lda=256 each)
// AKIND 3: A0 f32 plain, lda=K
// AKIND 4: dual: cols [0,256) bf16 A0, [256,512) f32 A1   (lda=256 each)
// BIAS  1: bias[col] plain     2: dege[row]>0 ? bias[col] : 0
// 128x128 tile, 256 threads, 8x8/thread, K-major LDS.
// ---------------------------------------------------------------------------
#define BM 128
#define BN 128
#define BK 16

template <int AKIND, int BIAS, bool ACCUM>
__global__ __launch_bounds__(256) void gemm_tn(
    const void* __restrict__ A0v, const void* __restrict__ A1v,
    const float* __restrict__ B, u16* __restrict__ C,
    int M, int Ncol, int K,
    const float* __restrict__ bias, const float* __restrict__ dege)
{
    __shared__ __align__(16) float As[BK][BM + 4];
    __shared__ __align__(16) float Bs[BK][BN + 4];
    const int bm = blockIdx.y * BM;
    const int bn = blockIdx.x * BN;
    const int tid = threadIdx.x;
    const int tx = tid & 15;
    const int ty = tid >> 4;

    float acc[8][8] = {};

    for (int k0 = 0; k0 < K; k0 += BK) {
#pragma unroll
        for (int r = 0; r < 2; ++r) {
            int idx = tid + r * 256;       // 4-elem slot in [0,512)
            int row = idx >> 2;            // [0,128)
            int cc = (idx & 3) << 2;       // {0,4,8,12}
            float4 v = make_float4(0.f, 0.f, 0.f, 0.f);
            if (bm + row < M) {
                if constexpr (AKIND == 0) {
                    const float* A = (const float*)A0v;
                    v = *reinterpret_cast<const float4*>(
                        A + (size_t)(bm + row) * K + k0 + cc);
                    float s = 1.0f / fmaxf(dege[bm + row], 1.0f);
                    v.x *= s; v.y *= s; v.z *= s; v.w *= s;
                } else if constexpr (AKIND == 3) {
                    const float* A = (const float*)A0v;
                    v = *reinterpret_cast<const float4*>(
                        A + (size_t)(bm + row) * K + k0 + cc);
                } else if constexpr (AKIND == 1) {
                    const u16* A = (const u16*)A0v;
                    ushort4 uv = *reinterpret_cast<const ushort4*>(
                        A + (size_t)(bm + row) * K + k0 + cc);
                    v = make_float4(b2f(uv.x), b2f(uv.y), b2f(uv.z), b2f(uv.w));
                } else {
                    // dual-A: [0,256) bf16 A0; [256,512) A1 (bf16 if AKIND==2, f32 if 4)
                    if (k0 < 256) {
                        const u16* A = (const u16*)A0v;
                        ushort4 uv = *reinterpret_cast<const ushort4*>(
                            A + (size_t)(bm + row) * 256 + k0 + cc);
                        v = make_float4(b2f(uv.x), b2f(uv.y), b2f(uv.z), b2f(uv.w));
                    } else if constexpr (AKIND == 2) {
                        const u16* A = (const u16*)A1v;
                        ushort4 uv = *reinterpret_cast<const ushort4*>(
                            A + (size_t)(bm + row) * 256 + (k0 - 256) + cc);
                        v = make_float4(b2f(uv.x), b2f(uv.y), b2f(uv.z), b2f(uv.w));
                    } else {
                        const float* A = (const float*)A1v;
                        v = *reinterpret_cast<const float4*>(
                            A + (size_t)(bm + row) * 256 + (k0 - 256) + cc);
                    }
                }
            }
            As[cc + 0][row] = v.x; As[cc + 1][row] = v.y;
            As[cc + 2][row] = v.z; As[cc + 3][row] = v.w;
            float4 wv = make_float4(0.f, 0.f, 0.f, 0.f);
            if (bn + row < Ncol)
                wv = *reinterpret_cast<const float4*>(B + (size_t)(bn + row) * K + k0 + cc);
            Bs[cc + 0][row] = wv.x; Bs[cc + 1][row] = wv.y;
            Bs[cc + 2][row] = wv.z; Bs[cc + 3][row] = wv.w;
        }
        __syncthreads();
#pragma unroll
        for (int kk = 0; kk < BK; ++kk) {
            float a[8], b[8];
            *reinterpret_cast<float4*>(&a[0]) = *reinterpret_cast<const float4*>(&As[kk][ty * 8]);
            *reinterpret_cast<float4*>(&a[4]) = *reinterpret_cast<const float4*>(&As[kk][ty * 8 + 4]);
            *reinterpret_cast<float4*>(&b[0]) = *reinterpret_cast<const float4*>(&Bs[kk][tx * 4]);
            *reinterpret_cast<float4*>(&b[4]) = *reinterpret_cast<const float4*>(&Bs[kk][tx * 4 + 64]);
#pragma unroll
            for (int i = 0; i < 8; ++i)
#pragma unroll
                for (int j = 0; j < 8; ++j)
                    acc[i][j] = fmaf(a[i], b[j], acc[i][j]);
        }
        __syncthreads();
    }

    // epilogue
    float bcol[8];
#pragma unroll
    for (int j = 0; j < 4; ++j) {
        bcol[j]     = bias[bn + tx * 4 + j];
        bcol[4 + j] = bias[bn + 64 + tx * 4 + j];
    }
#pragma unroll
    for (int i = 0; i < 8; ++i) {
        int row = bm + ty * 8 + i;
        if (row >= M) break;
        float bm_ = 1.0f;
        if (BIAS == 2) bm_ = (dege[row] > 0.f) ? 1.0f : 0.0f;
        float o[8];
#pragma unroll
        for (int j = 0; j < 8; ++j) o[j] = acc[i][j] + bm_ * bcol[j];
        u16* c0 = C + (size_t)row * Ncol + bn + tx * 4;
        u16* c1 = C + (size_t)row * Ncol + bn + 64 + tx * 4;
        if (ACCUM) {
            ushort4 e0 = *reinterpret_cast<const ushort4*>(c0);
            ushort4 e1 = *reinterpret_cast<const ushort4*>(c1);
            o[0] += b2f(e0.x); o[1] += b2f(e0.y); o[2] += b2f(e0.z); o[3] += b2f(e0.w);
            o[4] += b2f(e1.x); o[5] += b2f(e1.y); o[6] += b2f(e1.z); o[7] += b2f(e1.w);
        }
        ushort4 p0, p1;
        p0.x = f2b(o[0]); p0.y = f2b(o[1]); p0.z = f2b(o[2]); p0.w = f2b(o[3]);
        p1.x = f2b(o[4]); p1.y = f2b(o[5]); p1.z = f2b(o[6]); p1.w = f2b(o[7]);
        *reinterpret_cast<ushort4*>(c0) = p0;
        *reinterpret_cast<ushort4*>(c1) = p1;
    }
}

// ---------------------------------------------------------------------------
// fused GRU cell + LayerNorm, one block (256 thr) per node
// rz/nin/hn bf16; h read bf16 if HBF else f32; out written f32 if OF32 else bf16
// ---------------------------------------------------------------------------
template <bool HBF, bool OF32>
__global__ __launch_bounds__(256) void gru_ln_kernel(
    const u16* __restrict__ rz, const u16* __restrict__ nin,
    const u16* __restrict__ hn, const void* __restrict__ hv,
    void* __restrict__ outv,
    const float* __restrict__ gamma, const float* __restrict__ beta)
{
    int n = blockIdx.x;
    int j = threadIdx.x;
    size_t b2 = (size_t)n * 512;
    size_t b1 = (size_t)n * D;

    float r = 1.f / (1.f + __expf(-b2f(rz[b2 + j])));
    float z = 1.f / (1.f + __expf(-b2f(rz[b2 + 256 + j])));
    float xn = b2f(nin[b1 + j]) + r * b2f(hn[b1 + j]);
    float nn = 2.f / (1.f + __expf(-2.f * xn)) - 1.f;   // tanh
    float hv_;
    if (HBF) hv_ = b2f(((const u16*)hv)[b1 + j]);
    else     hv_ = ((const float*)hv)[b1 + j];
    float hnew = (1.f - z) * nn + z * hv_;

    float s1 = hnew, s2 = hnew * hnew;
#pragma unroll
    for (int o = 32; o > 0; o >>= 1) {
        s1 += __shfl_down(s1, o);
        s2 += __shfl_down(s2, o);
    }
    __shared__ float red[8];
    int wv = j >> 6;
    if ((j & 63) == 0) { red[wv] = s1; red[4 + wv] = s2; }
    __syncthreads();
    float sum = red[0] + red[1] + red[2] + red[3];
    float ssq = red[4] + red[5] + red[6] + red[7];
    float mu = sum * (1.f / D);
    float var = ssq * (1.f / D) - mu * mu;
    float rstd = rsqrtf(var + 1e-5f);
    float res = (hnew - mu) * rstd * gamma[j] + beta[j];
    if (OF32) ((float*)outv)[b1 + j] = res;
    else      ((u16*)outv)[b1 + j] = f2b(res);
}

// ---------------------------------------------------------------------------
// ws-too-small signal: fill f32 output with ws_size in MiB
// ---------------------------------------------------------------------------
__global__ __launch_bounds__(256) void fill_kernel(float* __restrict__ out, float val, int n)
{
    int i = blockIdx.x * 256 + threadIdx.x;
    if (i < n) out[i] = val;
}

// ---------------------------------------------------------------------------
extern "C" void kernel_launch(void* const* d_in, const int* in_sizes, int n_in,
                              void* d_out, int out_size, void* d_ws, size_t ws_size,
                              hipStream_t stream)
{
    const float* x    = (const float*)d_in[0];
    const int* se[4] = {(const int*)d_in[1], (const int*)d_in[5],
                        (const int*)d_in[9], (const int*)d_in[13]};
    const int* de[4] = {(const int*)d_in[2], (const int*)d_in[6],
                        (const int*)d_in[10], (const int*)d_in[14]};
    const float* We[4] = {(const float*)d_in[3], (const float*)d_in[7],
                          (const float*)d_in[11], (const float*)d_in[15]};
    const float* be[4] = {(const float*)d_in[4], (const float*)d_in[8],
                          (const float*)d_in[12], (const float*)d_in[16]};
    const float* W_ih = (const float*)d_in[17];
    const float* W_hh = (const float*)d_in[18];
    const float* b_ih = (const float*)d_in[19];
    const float* b_hh = (const float*)d_in[20];
    const float* gamma = (const float*)d_in[21];
    const float* beta  = (const float*)d_in[22];
    float* outf = (float*)d_out;          // d_out is f32 [N, D]

    const float* WnI = W_ih + (size_t)512 * 256;   // rows 512..767 of W_ih
    const float* WnH = W_hh + (size_t)512 * 256;
    const float* bnI = b_ih + 512;
    const float* bnH = b_hh + 512;

    // ---- workspace layout (bytes); proven to fit (R3/R4 ran at this size) ----
    char* base = (char*)d_ws;
    size_t off = 0;
    float* Hsum = (float*)(base + off);               // f32 [N,D]  (51.2 MB)
    u16*  rzb  = (u16*)(base + off);                  // alias: bf16 [N,512] (Hsum dead)
    off += (size_t)N_NODES * D * 4;
    u16* aggb = (u16*)(base + off); off += (size_t)N_NODES * D * 2;
    u16* ninb = (u16*)(base + off); off += (size_t)N_NODES * D * 2;
    u16* hnb  = (u16*)(base + off); off += (size_t)N_NODES * D * 2;
    u16* h1b  = (u16*)(base + off); off += (size_t)N_NODES * D * 2;
    float* deg = (float*)(base + off); off += (size_t)4 * N_NODES * 4;
    float* Wrz = (float*)(base + off); off += (size_t)512 * 512 * 4;
    float* brz = (float*)(base + off); off += 512 * 4;

    if (ws_size < off) {
        fill_kernel<<<(out_size + 255) / 256, 256, 0, stream>>>(
            outf, (float)(ws_size >> 20), out_size);
        return;
    }

    hipMemsetAsync(deg, 0, sizeof(float) * 4 * N_NODES, stream);
    prep_kernel<<<1024, 256, 0, stream>>>(W_ih, W_hh, b_ih, b_hh, Wrz, brz);
    deg_kernel<<<(4 * E_EDGES + 255) / 256, 256, 0, stream>>>(
        de[0], de[1], de[2], de[3], deg);

    const int gy = (N_NODES + BM - 1) / BM;   // 391
    for (int step = 0; step < 3; ++step) {
        // state chain: x (f32) -> h1b (bf16) -> outf (f32) -> outf (f32, in-place)
        const void* hcur = (step == 0) ? (const void*)x
                          : (step == 1) ? (const void*)h1b : (const void*)outf;
        const bool hbf = (step == 1);

        // agg = sum_e [ (Hsum_e/deg_e) @ W_e^T + (deg_e>0)*b_e ]   (bf16 rmw)
        for (int e = 0; e < 4; ++e) {
            hipMemsetAsync(Hsum, 0, sizeof(float) * (size_t)N_NODES * D, stream);
            if (hbf)
                scatter_kernel<true><<<E_EDGES / 4, 256, 0, stream>>>(hcur, se[e], de[e], Hsum);
            else
                scatter_kernel<false><<<E_EDGES / 4, 256, 0, stream>>>(hcur, se[e], de[e], Hsum);
            if (e == 0)
                gemm_tn<0, 2, false><<<dim3(2, gy), 256, 0, stream>>>(
                    Hsum, nullptr, We[e], aggb, N_NODES, D, D,
                    be[e], deg + (size_t)e * N_NODES);
            else
                gemm_tn<0, 2, true><<<dim3(2, gy), 256, 0, stream>>>(
                    Hsum, nullptr, We[e], aggb, N_NODES, D, D,
                    be[e], deg + (size_t)e * N_NODES);
        }

        // rz = [agg | h] @ Wrz^T + brz        (K=512, Ncol=512)
        if (hbf)
            gemm_tn<2, 1, false><<<dim3(4, gy), 256, 0, stream>>>(
                aggb, hcur, Wrz, rzb, N_NODES, 512, 512, brz, nullptr);
        else
            gemm_tn<4, 1, false><<<dim3(4, gy), 256, 0, stream>>>(
                aggb, hcur, Wrz, rzb, N_NODES, 512, 512, brz, nullptr);
        // i_n = agg @ WnI^T + bnI ; h_n = h @ WnH^T + bnH
        gemm_tn<1, 1, false><<<dim3(2, gy), 256, 0, stream>>>(
            aggb, nullptr, WnI, ninb, N_NODES, D, D, bnI, nullptr);
        if (hbf)
            gemm_tn<1, 1, false><<<dim3(2, gy), 256, 0, stream>>>(
                hcur, nullptr, WnH, hnb, N_NODES, D, D, bnH, nullptr);
        else
            gemm_tn<3, 1, false><<<dim3(2, gy), 256, 0, stream>>>(
                hcur, nullptr, WnH, hnb, N_NODES, D, D, bnH, nullptr);

        // step 0 -> h1b (bf16); steps 1,2 -> outf (f32; step2 in-place on outf)
        if (step == 0)
            gru_ln_kernel<false, false><<<N_NODES, 256, 0, stream>>>(
                rzb, ninb, hnb, hcur, h1b, gamma, beta);
        else if (step == 1)
            gru_ln_kernel<true, true><<<N_NODES, 256, 0, stream>>>(
                rzb, ninb, hnb, hcur, outf, gamma, beta);
        else
            gru_ln_kernel<false, true><<<N_NODES, 256, 0, stream>>>(
                rzb, ninb, hnb, hcur, outf, gamma, beta);
    }
}

// Round 6
// 3410.037 us; speedup vs baseline: 4.4242x; 4.4242x over previous
//
#include <hip/hip_runtime.h>
#include <hip/hip_bf16.h>
#include <cstddef>

#define N_NODES 50000
#define E_EDGES 300000
#define D 256

typedef unsigned short u16;

__device__ __forceinline__ float b2f(u16 u) {
    return __uint_as_float(((unsigned)u) << 16);
}
__device__ __forceinline__ u16 f2b(float f) {
    __hip_bfloat16 h = __float2bfloat16(f);
    return *reinterpret_cast<u16*>(&h);
}

// ---------------------------------------------------------------------------
// prep: pack weights (all f32 in place except these):
//   Bcat[j][e*256+k] = W_e[j][k]            (256 x 1024 f32)
//   Wrz[j][k] = k<256 ? W_ih[j][k] : W_hh[j][k-256]   (512 x 512)
//   brz[j] = b_ih[j]+b_hh[j]; be4[e*256+k] = b_e[k]
// ---------------------------------------------------------------------------
__global__ __launch_bounds__(256) void prep_kernel(
    const float* __restrict__ W0, const float* __restrict__ W1,
    const float* __restrict__ W2, const float* __restrict__ W3,
    const float* __restrict__ b0, const float* __restrict__ b1,
    const float* __restrict__ b2, const float* __restrict__ b3,
    const float* __restrict__ W_ih, const float* __restrict__ W_hh,
    const float* __restrict__ b_ih, const float* __restrict__ b_hh,
    float* __restrict__ Bcat, float* __restrict__ Wrz,
    float* __restrict__ brz, float* __restrict__ be4)
{
    int t = blockIdx.x * 256 + threadIdx.x;     // [0, 262144)
    {
        int j = t >> 10;
        int c = t & 1023;
        int e = c >> 8;
        int k = c & 255;
        const float* W = (e == 0) ? W0 : (e == 1) ? W1 : (e == 2) ? W2 : W3;
        Bcat[t] = W[j * 256 + k];
    }
    {
        int j = t >> 9;
        int k = t & 511;
        Wrz[t] = (k < 256) ? W_ih[j * 256 + k] : W_hh[j * 256 + (k - 256)];
    }
    if (t < 512) brz[t] = b_ih[t] + b_hh[t];
    if (t < 1024) {
        int e = t >> 8, k = t & 255;
        const float* b = (e == 0) ? b0 : (e == 1) ? b1 : (e == 2) ? b2 : b3;
        be4[t] = b[k];
    }
}

// ---------------------------------------------------------------------------
// CSR build (edges launch-invariant; rebuilt identically each call)
// ---------------------------------------------------------------------------
__global__ __launch_bounds__(256) void cnt_kernel(
    const int* __restrict__ d0, const int* __restrict__ d1,
    const int* __restrict__ d2, const int* __restrict__ d3,
    int* __restrict__ rowptr)           // [4][N+1], pre-zeroed
{
    int i = blockIdx.x * 256 + threadIdx.x;
    if (i >= 4 * E_EDGES) return;
    int e = i / E_EDGES;
    int k = i - e * E_EDGES;
    const int* dp = (e == 0) ? d0 : (e == 1) ? d1 : (e == 2) ? d2 : d3;
    atomicAdd(&rowptr[e * (N_NODES + 1) + dp[k] + 1], 1);
}

// inclusive scan of rowptr[e][0..N] per etype; 4 blocks x 1024 threads
__global__ __launch_bounds__(1024) void scan_kernel(int* __restrict__ rowptr)
{
    int e = blockIdx.x;
    int* rp = rowptr + e * (N_NODES + 1);
    __shared__ int s[1024];
    int t = threadIdx.x;
    int carry = 0;
    const int chunks = (N_NODES + 1 + 1023) / 1024;   // 49
    for (int c = 0; c < chunks; ++c) {
        int idx = c * 1024 + t;
        int v = (idx <= N_NODES) ? rp[idx] : 0;
        s[t] = v;
        __syncthreads();
#pragma unroll
        for (int o = 1; o < 1024; o <<= 1) {
            int u = (t >= o) ? s[t - o] : 0;
            __syncthreads();
            s[t] += u;
            __syncthreads();
        }
        if (idx <= N_NODES) rp[idx] = s[t] + carry;
        int tot = s[1023];
        __syncthreads();
        carry += tot;
    }
}

__global__ __launch_bounds__(256) void cursor_kernel(
    const int* __restrict__ rowptr, int* __restrict__ cursor)
{
    int i = blockIdx.x * 256 + threadIdx.x;
    if (i >= 4 * N_NODES) return;
    int e = i / N_NODES;
    int n = i - e * N_NODES;
    cursor[i] = rowptr[e * (N_NODES + 1) + n];
}

__global__ __launch_bounds__(256) void fill_csr_kernel(
    const int* __restrict__ s0, const int* __restrict__ d0,
    const int* __restrict__ s1, const int* __restrict__ d1,
    const int* __restrict__ s2, const int* __restrict__ d2,
    const int* __restrict__ s3, const int* __restrict__ d3,
    int* __restrict__ cursor, int* __restrict__ colb)   // colb [4][E]
{
    int i = blockIdx.x * 256 + threadIdx.x;
    if (i >= 4 * E_EDGES) return;
    int e = i / E_EDGES;
    int k = i - e * E_EDGES;
    const int* sp = (e == 0) ? s0 : (e == 1) ? s1 : (e == 2) ? s2 : s3;
    const int* dp = (e == 0) ? d0 : (e == 1) ? d1 : (e == 2) ? d2 : d3;
    int dst = dp[k];
    int slot = atomicAdd(&cursor[e * N_NODES + dst], 1);
    colb[(size_t)e * E_EDGES + slot] = sp[k];
}

__global__ __launch_bounds__(256) void degmask_kernel(
    const int* __restrict__ rowptr, int* __restrict__ degmask)
{
    int n = blockIdx.x * 256 + threadIdx.x;
    if (n >= N_NODES) return;
    int m = 0;
#pragma unroll
    for (int e = 0; e < 4; ++e) {
        const int* rp = rowptr + e * (N_NODES + 1);
        m |= (rp[n + 1] > rp[n]) ? (1 << e) : 0;
    }
    degmask[n] = m;
}

// ---------------------------------------------------------------------------
// gather4: Hmean4[n][e*256+c] = mean over in-edges(e) of h[src][c]  (bf16 out)
// one block per node; wave w = etype w; h is f32 state
// ---------------------------------------------------------------------------
__global__ __launch_bounds__(256) void gather4_kernel(
    const float* __restrict__ h, const int* __restrict__ rowptr,
    const int* __restrict__ colb, u16* __restrict__ Hmean4)
{
    int n = blockIdx.x;
    int e = threadIdx.x >> 6;
    int lane = threadIdx.x & 63;
    const int* rp = rowptr + e * (N_NODES + 1);
    const int* cb = colb + (size_t)e * E_EDGES;
    int beg = rp[n], end = rp[n + 1];
    float4 acc = make_float4(0.f, 0.f, 0.f, 0.f);
    for (int j = beg; j < end; ++j) {
        int src = cb[j];
        float4 v = *reinterpret_cast<const float4*>(h + (size_t)src * D + lane * 4);
        acc.x += v.x; acc.y += v.y; acc.z += v.z; acc.w += v.w;
    }
    float s = (end > beg) ? 1.0f / (float)(end - beg) : 0.0f;
    ushort4 o;
    o.x = f2b(acc.x * s); o.y = f2b(acc.y * s);
    o.z = f2b(acc.z * s); o.w = f2b(acc.w * s);
    *reinterpret_cast<ushort4*>(Hmean4 + (size_t)n * 1024 + e * 256 + lane * 4) = o;
}

// ---------------------------------------------------------------------------
// C[M,Ncol](bf16) = op(A)[M,K] @ B[Ncol,K]^T + bias
// AKIND 1: A0 bf16, lda=K
// AKIND 3: A0 f32,  lda=K
// AKIND 4: dual: cols [0,256) bf16 A0, [256,512) f32 A1 (lda=256 each)
// BIAS  1: bias[col]          3: sum_e (degmask[row]>>e&1) * bias[e*256+col]
// 128x128 tile, 256 threads, 8x8/thread, K-major LDS.
// ---------------------------------------------------------------------------
#define BM 128
#define BN 128
#define BK 16

template <int AKIND, int BIAS>
__global__ __launch_bounds__(256) void gemm_tn(
    const void* __restrict__ A0v, const void* __restrict__ A1v,
    const float* __restrict__ B, u16* __restrict__ C,
    int M, int Ncol, int K,
    const float* __restrict__ bias, const int* __restrict__ degmask)
{
    __shared__ __align__(16) float As[BK][BM + 4];
    __shared__ __align__(16) float Bs[BK][BN + 4];
    const int bm = blockIdx.y * BM;
    const int bn = blockIdx.x * BN;
    const int tid = threadIdx.x;
    const int tx = tid & 15;
    const int ty = tid >> 4;

    float acc[8][8] = {};

    for (int k0 = 0; k0 < K; k0 += BK) {
#pragma unroll
        for (int r = 0; r < 2; ++r) {
            int idx = tid + r * 256;       // 4-elem slot in [0,512)
            int row = idx >> 2;            // [0,128)
            int cc = (idx & 3) << 2;       // {0,4,8,12}
            float4 v = make_float4(0.f, 0.f, 0.f, 0.f);
            if (bm + row < M) {
                if constexpr (AKIND == 1) {
                    const u16* A = (const u16*)A0v;
                    ushort4 uv = *reinterpret_cast<const ushort4*>(
                        A + (size_t)(bm + row) * K + k0 + cc);
                    v = make_float4(b2f(uv.x), b2f(uv.y), b2f(uv.z), b2f(uv.w));
                } else if constexpr (AKIND == 3) {
                    const float* A = (const float*)A0v;
                    v = *reinterpret_cast<const float4*>(
                        A + (size_t)(bm + row) * K + k0 + cc);
                } else {
                    if (k0 < 256) {
                        const u16* A = (const u16*)A0v;
                        ushort4 uv = *reinterpret_cast<const ushort4*>(
                            A + (size_t)(bm + row) * 256 + k0 + cc);
                        v = make_float4(b2f(uv.x), b2f(uv.y), b2f(uv.z), b2f(uv.w));
                    } else {
                        const float* A = (const float*)A1v;
                        v = *reinterpret_cast<const float4*>(
                            A + (size_t)(bm + row) * 256 + (k0 - 256) + cc);
                    }
                }
            }
            As[cc + 0][row] = v.x; As[cc + 1][row] = v.y;
            As[cc + 2][row] = v.z; As[cc + 3][row] = v.w;
            float4 wv = make_float4(0.f, 0.f, 0.f, 0.f);
            if (bn + row < Ncol)
                wv = *reinterpret_cast<const float4*>(B + (size_t)(bn + row) * K + k0 + cc);
            Bs[cc + 0][row] = wv.x; Bs[cc + 1][row] = wv.y;
            Bs[cc + 2][row] = wv.z; Bs[cc + 3][row] = wv.w;
        }
        __syncthreads();
#pragma unroll
        for (int kk = 0; kk < BK; ++kk) {
            float a[8], b[8];
            *reinterpret_cast<float4*>(&a[0]) = *reinterpret_cast<const float4*>(&As[kk][ty * 8]);
            *reinterpret_cast<float4*>(&a[4]) = *reinterpret_cast<const float4*>(&As[kk][ty * 8 + 4]);
            *reinterpret_cast<float4*>(&b[0]) = *reinterpret_cast<const float4*>(&Bs[kk][tx * 4]);
            *reinterpret_cast<float4*>(&b[4]) = *reinterpret_cast<const float4*>(&Bs[kk][tx * 4 + 64]);
#pragma unroll
            for (int i = 0; i < 8; ++i)
#pragma unroll
                for (int j = 0; j < 8; ++j)
                    acc[i][j] = fmaf(a[i], b[j], acc[i][j]);
        }
        __syncthreads();
    }

    // epilogue
    float bcol[8];
    float bcol4[4][8];
    if constexpr (BIAS == 1) {
#pragma unroll
        for (int j = 0; j < 4; ++j) {
            bcol[j]     = bias[bn + tx * 4 + j];
            bcol[4 + j] = bias[bn + 64 + tx * 4 + j];
        }
    } else {
#pragma unroll
        for (int e = 0; e < 4; ++e)
#pragma unroll
            for (int j = 0; j < 4; ++j) {
                bcol4[e][j]     = bias[e * 256 + bn + tx * 4 + j];
                bcol4[e][4 + j] = bias[e * 256 + bn + 64 + tx * 4 + j];
            }
    }
#pragma unroll
    for (int i = 0; i < 8; ++i) {
        int row = bm + ty * 8 + i;
        if (row >= M) break;
        float o[8];
        if constexpr (BIAS == 1) {
#pragma unroll
            for (int j = 0; j < 8; ++j) o[j] = acc[i][j] + bcol[j];
        } else {
            int bits = degmask[row];
            float m0 = (bits & 1) ? 1.f : 0.f;
            float m1 = (bits & 2) ? 1.f : 0.f;
            float m2 = (bits & 4) ? 1.f : 0.f;
            float m3 = (bits & 8) ? 1.f : 0.f;
#pragma unroll
            for (int j = 0; j < 8; ++j)
                o[j] = acc[i][j] + m0 * bcol4[0][j] + m1 * bcol4[1][j]
                                 + m2 * bcol4[2][j] + m3 * bcol4[3][j];
        }
        ushort4 p0, p1;
        p0.x = f2b(o[0]); p0.y = f2b(o[1]); p0.z = f2b(o[2]); p0.w = f2b(o[3]);
        p1.x = f2b(o[4]); p1.y = f2b(o[5]); p1.z = f2b(o[6]); p1.w = f2b(o[7]);
        *reinterpret_cast<ushort4*>(C + (size_t)row * Ncol + bn + tx * 4) = p0;
        *reinterpret_cast<ushort4*>(C + (size_t)row * Ncol + bn + 64 + tx * 4) = p1;
    }
}

// ---------------------------------------------------------------------------
// fused GRU cell + LayerNorm, one block (256 thr) per node
// rz/nin/hn bf16; h f32; out f32 (in-place on h allowed: read-before-write)
// ---------------------------------------------------------------------------
__global__ __launch_bounds__(256) void gru_ln_kernel(
    const u16* __restrict__ rz, const u16* __restrict__ nin,
    const u16* __restrict__ hn, const float* __restrict__ h,
    float* __restrict__ out,
    const float* __restrict__ gamma, const float* __restrict__ beta)
{
    int n = blockIdx.x;
    int j = threadIdx.x;
    size_t b2 = (size_t)n * 512;
    size_t b1 = (size_t)n * D;

    float r = 1.f / (1.f + __expf(-b2f(rz[b2 + j])));
    float z = 1.f / (1.f + __expf(-b2f(rz[b2 + 256 + j])));
    float xn = b2f(nin[b1 + j]) + r * b2f(hn[b1 + j]);
    float nn = 2.f / (1.f + __expf(-2.f * xn)) - 1.f;   // tanh
    float hv = h[b1 + j];
    float hnew = (1.f - z) * nn + z * hv;

    float s1 = hnew, s2 = hnew * hnew;
#pragma unroll
    for (int o = 32; o > 0; o >>= 1) {
        s1 += __shfl_down(s1, o);
        s2 += __shfl_down(s2, o);
    }
    __shared__ float red[8];
    int wv = j >> 6;
    if ((j & 63) == 0) { red[wv] = s1; red[4 + wv] = s2; }
    __syncthreads();
    float sum = red[0] + red[1] + red[2] + red[3];
    float ssq = red[4] + red[5] + red[6] + red[7];
    float mu = sum * (1.f / D);
    float var = ssq * (1.f / D) - mu * mu;
    float rstd = rsqrtf(var + 1e-5f);
    out[b1 + j] = (hnew - mu) * rstd * gamma[j] + beta[j];
}

// ---------------------------------------------------------------------------
// ws-too-small signal: fill f32 output with ws_size in MiB
// ---------------------------------------------------------------------------
__global__ __launch_bounds__(256) void wsfail_kernel(float* __restrict__ out, float val, int n)
{
    int i = blockIdx.x * 256 + threadIdx.x;
    if (i < n) out[i] = val;
}

// ---------------------------------------------------------------------------
extern "C" void kernel_launch(void* const* d_in, const int* in_sizes, int n_in,
                              void* d_out, int out_size, void* d_ws, size_t ws_size,
                              hipStream_t stream)
{
    const float* x    = (const float*)d_in[0];
    const int* se[4] = {(const int*)d_in[1], (const int*)d_in[5],
                        (const int*)d_in[9], (const int*)d_in[13]};
    const int* de[4] = {(const int*)d_in[2], (const int*)d_in[6],
                        (const int*)d_in[10], (const int*)d_in[14]};
    const float* We[4] = {(const float*)d_in[3], (const float*)d_in[7],
                          (const float*)d_in[11], (const float*)d_in[15]};
    const float* be[4] = {(const float*)d_in[4], (const float*)d_in[8],
                          (const float*)d_in[12], (const float*)d_in[16]};
    const float* W_ih = (const float*)d_in[17];
    const float* W_hh = (const float*)d_in[18];
    const float* b_ih = (const float*)d_in[19];
    const float* b_hh = (const float*)d_in[20];
    const float* gamma = (const float*)d_in[21];
    const float* beta  = (const float*)d_in[22];
    float* outf = (float*)d_out;          // f32 [N, D]; also the state buffer

    const float* WnI = W_ih + (size_t)512 * 256;   // rows 512..767
    const float* WnH = W_hh + (size_t)512 * 256;
    const float* bnI = b_ih + 512;
    const float* bnH = b_hh + 512;

    // ---- workspace layout (bytes), total ~137 MB (< 155.5 MB proven-safe) ----
    char* base = (char*)d_ws;
    size_t off = 0;
    u16* Hmean4 = (u16*)(base + off);                 // bf16 [N,1024] (102.4 MB)
    u16* rzb    = (u16*)(base + off);                 // alias (Hmean4 dead after agg)
    u16* ninb   = (u16*)(base + off + (size_t)N_NODES * 512 * 2);
    u16* hnb    = (u16*)(base + off + (size_t)N_NODES * 768 * 2);
    off += (size_t)N_NODES * 1024 * 2;
    u16* aggb = (u16*)(base + off); off += (size_t)N_NODES * D * 2;   // 25.6 MB
    int* rowptr = (int*)(base + off); off += (size_t)4 * (N_NODES + 1) * 4 + 32;
    int* colb   = (int*)(base + off); off += (size_t)4 * E_EDGES * 4;
    int* cursor = (int*)(base + off); off += (size_t)4 * N_NODES * 4;
    int* degmask = (int*)(base + off); off += (size_t)N_NODES * 4;
    float* Bcat = (float*)(base + off); off += (size_t)256 * 1024 * 4;
    float* Wrz  = (float*)(base + off); off += (size_t)512 * 512 * 4;
    float* brz  = (float*)(base + off); off += 512 * 4;
    float* be4  = (float*)(base + off); off += 1024 * 4;

    if (ws_size < off) {
        wsfail_kernel<<<(out_size + 255) / 256, 256, 0, stream>>>(
            outf, (float)(ws_size >> 20), out_size);
        return;
    }

    // ---- CSR build + weight prep (once per launch) ----
    hipMemsetAsync(rowptr, 0, (size_t)4 * (N_NODES + 1) * 4, stream);
    prep_kernel<<<1024, 256, 0, stream>>>(
        We[0], We[1], We[2], We[3], be[0], be[1], be[2], be[3],
        W_ih, W_hh, b_ih, b_hh, Bcat, Wrz, brz, be4);
    cnt_kernel<<<(4 * E_EDGES + 255) / 256, 256, 0, stream>>>(
        de[0], de[1], de[2], de[3], rowptr);
    scan_kernel<<<4, 1024, 0, stream>>>(rowptr);
    cursor_kernel<<<(4 * N_NODES + 255) / 256, 256, 0, stream>>>(rowptr, cursor);
    fill_csr_kernel<<<(4 * E_EDGES + 255) / 256, 256, 0, stream>>>(
        se[0], de[0], se[1], de[1], se[2], de[2], se[3], de[3], cursor, colb);
    degmask_kernel<<<(N_NODES + 255) / 256, 256, 0, stream>>>(rowptr, degmask);

    const int gy = (N_NODES + BM - 1) / BM;   // 391
    for (int step = 0; step < 3; ++step) {
        const float* hcur = (step == 0) ? x : outf;

        // Hmean4[n, e*256+c] = mean of in-neighbors' h  (bf16)
        gather4_kernel<<<N_NODES, 256, 0, stream>>>(hcur, rowptr, colb, Hmean4);

        // agg = Hmean4 @ Bcat^T + sum_e mask_e b_e      (K=1024 fused etype sum)
        gemm_tn<1, 3><<<dim3(2, gy), 256, 0, stream>>>(
            Hmean4, nullptr, Bcat, aggb, N_NODES, D, 1024, be4, degmask);

        // rz = [agg | h] @ Wrz^T + brz                  (K=512, Ncol=512)
        gemm_tn<4, 1><<<dim3(4, gy), 256, 0, stream>>>(
            aggb, hcur, Wrz, rzb, N_NODES, 512, 512, brz, nullptr);
        // i_n = agg @ WnI^T + bnI ; h_n = h @ WnH^T + bnH
        gemm_tn<1, 1><<<dim3(2, gy), 256, 0, stream>>>(
            aggb, nullptr, WnI, ninb, N_NODES, D, D, bnI, nullptr);
        gemm_tn<3, 1><<<dim3(2, gy), 256, 0, stream>>>(
            hcur, nullptr, WnH, hnb, N_NODES, D, D, bnH, nullptr);

        // state update (f32, in d_out; in-place safe elementwise)
        gru_ln_kernel<<<N_NODES, 256, 0, stream>>>(
            rzb, ninb, hnb, hcur, outf, gamma, beta);
    }
}

// Round 7
// 1395.124 us; speedup vs baseline: 10.8137x; 2.4443x over previous
//
#include <hip/hip_runtime.h>
#include <hip/hip_bf16.h>
#include <cstddef>

#define N_NODES 50000
#define E_EDGES 300000
#define D 256
#define M_PAD 50048           // 391 * 128

typedef unsigned short u16;
typedef __attribute__((ext_vector_type(8))) short bf16x8;   // 8 bf16 = 4 VGPRs
typedef __attribute__((ext_vector_type(4))) float f32x4;

__device__ __forceinline__ float b2f(u16 u) {
    return __uint_as_float(((unsigned)u) << 16);
}
__device__ __forceinline__ u16 f2b(float f) {
    __hip_bfloat16 h = __float2bfloat16(f);
    return *reinterpret_cast<u16*>(&h);
}
__device__ __forceinline__ void async16(const u16* g, u16* l) {
    __builtin_amdgcn_global_load_lds(
        (const __attribute__((address_space(1))) void*)g,
        (__attribute__((address_space(3))) void*)l, 16, 0, 0);
}

// ---------------------------------------------------------------------------
// prep: pack all weights to bf16 once.
//   Wrz_b[j][k]  = k<256 ? W_ih[j][k] : W_hh[j][k-256]         (512x512)
//   Bcat_b[p][j][el*256+kk] = W_{2p+el}[j][kk]                 (2 x 256 x 512)
//   WnI_b/WnH_b[j][k] = W_ih/W_hh[512+j][k]                    (256x256)
//   brz[j] = b_ih[j]+b_hh[j] (f32); be4[e][k] = b_e[k] (f32)
// ---------------------------------------------------------------------------
__global__ __launch_bounds__(256) void prep_kernel(
    const float* __restrict__ W0, const float* __restrict__ W1,
    const float* __restrict__ W2, const float* __restrict__ W3,
    const float* __restrict__ b0, const float* __restrict__ b1,
    const float* __restrict__ b2, const float* __restrict__ b3,
    const float* __restrict__ W_ih, const float* __restrict__ W_hh,
    const float* __restrict__ b_ih, const float* __restrict__ b_hh,
    u16* __restrict__ Wrz_b, u16* __restrict__ Bcat_b,
    u16* __restrict__ WnI_b, u16* __restrict__ WnH_b,
    float* __restrict__ brz, float* __restrict__ be4)
{
    int t = blockIdx.x * 256 + threadIdx.x;    // [0, 262144)
    {
        int j = t >> 9, k = t & 511;
        Wrz_b[t] = f2b(k < 256 ? W_ih[j * 256 + k] : W_hh[j * 256 + (k - 256)]);
    }
    {
        int p = t >> 17, rem = t & 131071;
        int j = rem >> 9, k = rem & 511;
        int e = p * 2 + (k >> 8), kk = k & 255;
        const float* W = (e == 0) ? W0 : (e == 1) ? W1 : (e == 2) ? W2 : W3;
        Bcat_b[t] = f2b(W[j * 256 + kk]);
    }
    if (t < 65536) {
        WnI_b[t] = f2b(W_ih[131072 + t]);
        WnH_b[t] = f2b(W_hh[131072 + t]);
    }
    if (t < 512) brz[t] = b_ih[t] + b_hh[t];
    if (t < 1024) {
        int e = t >> 8, k = t & 255;
        const float* b = (e == 0) ? b0 : (e == 1) ? b1 : (e == 2) ? b2 : b3;
        be4[t] = b[k];
    }
}

// ---------------------------------------------------------------------------
// CSR build (cursor-free: rowptr doubles as the fill cursor)
// post-fill semantics: beg(n) = n ? rp[n-1] : 0 ; end(n) = rp[n]
// ---------------------------------------------------------------------------
__global__ __launch_bounds__(256) void cnt_kernel(
    const int* __restrict__ d0, const int* __restrict__ d1,
    const int* __restrict__ d2, const int* __restrict__ d3,
    int* __restrict__ rowptr)
{
    int i = blockIdx.x * 256 + threadIdx.x;
    if (i >= 4 * E_EDGES) return;
    int e = i / E_EDGES;
    int k = i - e * E_EDGES;
    const int* dp = (e == 0) ? d0 : (e == 1) ? d1 : (e == 2) ? d2 : d3;
    atomicAdd(&rowptr[e * (N_NODES + 1) + dp[k] + 1], 1);
}

__global__ __launch_bounds__(1024) void scan_kernel(int* __restrict__ rowptr)
{
    int e = blockIdx.x;
    int* rp = rowptr + e * (N_NODES + 1);
    __shared__ int s[1024];
    int t = threadIdx.x;
    int carry = 0;
    const int chunks = (N_NODES + 1 + 1023) / 1024;   // 49
    for (int c = 0; c < chunks; ++c) {
        int idx = c * 1024 + t;
        int v = (idx <= N_NODES) ? rp[idx] : 0;
        s[t] = v;
        __syncthreads();
#pragma unroll
        for (int o = 1; o < 1024; o <<= 1) {
            int u = (t >= o) ? s[t - o] : 0;
            __syncthreads();
            s[t] += u;
            __syncthreads();
        }
        if (idx <= N_NODES) rp[idx] = s[t] + carry;
        int tot = s[1023];
        __syncthreads();
        carry += tot;
    }
}

__global__ __launch_bounds__(256) void fill_csr_kernel(
    const int* __restrict__ s0, const int* __restrict__ d0,
    const int* __restrict__ s1, const int* __restrict__ d1,
    const int* __restrict__ s2, const int* __restrict__ d2,
    const int* __restrict__ s3, const int* __restrict__ d3,
    int* __restrict__ rowptr, u16* __restrict__ colb)
{
    int i = blockIdx.x * 256 + threadIdx.x;
    if (i >= 4 * E_EDGES) return;
    int e = i / E_EDGES;
    int k = i - e * E_EDGES;
    const int* sp = (e == 0) ? s0 : (e == 1) ? s1 : (e == 2) ? s2 : s3;
    const int* dp = (e == 0) ? d0 : (e == 1) ? d1 : (e == 2) ? d2 : d3;
    int dst = dp[k];
    int slot = atomicAdd(&rowptr[e * (N_NODES + 1) + dst], 1);
    colb[(size_t)e * E_EDGES + slot] = (u16)sp[k];
}

__global__ __launch_bounds__(256) void degmask_kernel(
    const int* __restrict__ rowptr, unsigned char* __restrict__ degmask)
{
    int n = blockIdx.x * 256 + threadIdx.x;
    if (n >= N_NODES) return;
    int m = 0;
#pragma unroll
    for (int e = 0; e < 4; ++e) {
        const int* rp = rowptr + e * (N_NODES + 1);
        int beg = n ? rp[n - 1] : 0;
        if (rp[n] > beg) m |= (1 << e);
    }
    degmask[n] = (unsigned char)m;
}

// ---------------------------------------------------------------------------
// gather2: Hmean2[n][el*256+c] = mean over in-edges(2*pair+el) of h[src][c]
// 2 nodes per block; h is f32 state; output bf16
// ---------------------------------------------------------------------------
__global__ __launch_bounds__(256) void gather2_kernel(
    const float* __restrict__ h, const int* __restrict__ rowptr,
    const u16* __restrict__ colb, u16* __restrict__ Hmean2, int pair)
{
    int n = blockIdx.x * 2 + (threadIdx.x >> 7);
    int el = (threadIdx.x >> 6) & 1;
    int lane = threadIdx.x & 63;
    int e = pair * 2 + el;
    const int* rp = rowptr + e * (N_NODES + 1);
    int beg = n ? rp[n - 1] : 0;
    int end = rp[n];
    const u16* cb = colb + (size_t)e * E_EDGES;
    float ax = 0.f, ay = 0.f, az = 0.f, aw = 0.f;
    for (int j = beg; j < end; ++j) {
        int src = cb[j];
        float4 v = *reinterpret_cast<const float4*>(h + (size_t)src * D + lane * 4);
        ax += v.x; ay += v.y; az += v.z; aw += v.w;
    }
    float s = (end > beg) ? 1.f / (float)(end - beg) : 0.f;
    ushort4 o;
    o.x = f2b(ax * s); o.y = f2b(ay * s); o.z = f2b(az * s); o.w = f2b(aw * s);
    *reinterpret_cast<ushort4*>(Hmean2 + (size_t)n * 512 + el * 256 + lane * 4) = o;
}

// ---------------------------------------------------------------------------
// MFMA GEMM: C[N_NODES,Ncol](bf16) = A[.,K] @ B[Ncol,K]^T + bias (+C if ACCUM)
// A: k-element < KS*64 from A0 (bf16, lda0); else from A1 (f32, lda1, k-KS*64),
//    converted to bf16 during reg-staging.
// BIASK 1: bias0[col].  BIASK 3: per-row etype-pair masked bias0/bias1.
// 128x128 tile, BK=64, 256 thr = 4 waves (2x2), 64x64/wave, mfma 16x16x32 bf16.
// LDS: [128 rows][8 chunks of 16B], chunk XOR-swizzled by (row&7); staged via
// global_load_lds w/ pre-swizzled source (both-sides rule).
// ---------------------------------------------------------------------------
template <int BIASK, bool ACCUM>
__global__ __launch_bounds__(256) void gemm_mfma(
    const u16* __restrict__ A0, int lda0,
    const float* __restrict__ A1, int lda1,
    const u16* __restrict__ Bw, u16* __restrict__ C, int ldc,
    int Ncol, int K, int KS,
    const float* __restrict__ bias0, const float* __restrict__ bias1,
    const unsigned char* __restrict__ degmask, int mshift)
{
    __shared__ u16 As[8192];    // 128 x 64 bf16 (16 KB)
    __shared__ u16 Bs2[8192];
    const int bm = blockIdx.y * 128;
    const int bn = blockIdx.x * 128;
    const int tid = threadIdx.x;
    const int lane = tid & 63;
    const int wid = tid >> 6;
    const int wr = wid >> 1;
    const int wc = wid & 1;
    const int l15 = lane & 15;
    const int l4 = lane >> 4;

    int srow[4], schk[4];
#pragma unroll
    for (int i = 0; i < 4; ++i) {
        int q = (wid * 4 + i) * 64 + lane;
        srow[i] = q >> 3;                       // tile row / B row
        schk[i] = (q & 7) ^ (srow[i] & 7);      // source 16B chunk (pre-swizzle)
    }

    f32x4 acc[4][4];
#pragma unroll
    for (int i = 0; i < 4; ++i)
#pragma unroll
        for (int j = 0; j < 4; ++j)
            acc[i][j] = (f32x4){0.f, 0.f, 0.f, 0.f};

    const int nkt = K >> 6;
    for (int kt = 0; kt < nkt; ++kt) {
        if (kt < KS) {          // async bf16 A staging
#pragma unroll
            for (int i = 0; i < 4; ++i) {
                const u16* g = A0 + (size_t)(bm + srow[i]) * lda0 + kt * 64 + schk[i] * 8;
                async16(g, &As[(wid * 4 + i) * 512]);
            }
        } else {                // reg-staged f32 -> bf16 A staging
#pragma unroll
            for (int i = 0; i < 4; ++i) {
                int r = bm + srow[i];
                if (r > N_NODES - 1) r = N_NODES - 1;     // pad-row clamp
                const float* g = A1 + (size_t)r * lda1 + (kt - KS) * 64 + schk[i] * 8;
                float4 v0 = *reinterpret_cast<const float4*>(g);
                float4 v1 = *reinterpret_cast<const float4*>(g + 4);
                ushort4 p0, p1;
                p0.x = f2b(v0.x); p0.y = f2b(v0.y); p0.z = f2b(v0.z); p0.w = f2b(v0.w);
                p1.x = f2b(v1.x); p1.y = f2b(v1.y); p1.z = f2b(v1.z); p1.w = f2b(v1.w);
                u16* d = &As[((wid * 4 + i) * 64 + lane) * 8];
                *reinterpret_cast<ushort4*>(d) = p0;
                *reinterpret_cast<ushort4*>(d + 4) = p1;
            }
        }
#pragma unroll
        for (int i = 0; i < 4; ++i) {           // B always async bf16
            const u16* g = Bw + (size_t)(bn + srow[i]) * K + kt * 64 + schk[i] * 8;
            async16(g, &Bs2[(wid * 4 + i) * 512]);
        }
        __syncthreads();

#pragma unroll
        for (int kk = 0; kk < 2; ++kk) {
            bf16x8 a[4], b[4];
#pragma unroll
            for (int i = 0; i < 4; ++i) {
                int ar = wr * 64 + i * 16 + l15;
                a[i] = *reinterpret_cast<const bf16x8*>(
                    &As[ar * 64 + (((kk * 4 + l4) ^ (ar & 7)) << 3)]);
                int bc = wc * 64 + i * 16 + l15;
                b[i] = *reinterpret_cast<const bf16x8*>(
                    &Bs2[bc * 64 + (((kk * 4 + l4) ^ (bc & 7)) << 3)]);
            }
#pragma unroll
            for (int i = 0; i < 4; ++i)
#pragma unroll
                for (int j = 0; j < 4; ++j)
                    acc[i][j] = __builtin_amdgcn_mfma_f32_16x16x32_bf16(
                        a[i], b[j], acc[i][j], 0, 0, 0);
        }
        __syncthreads();
    }

    // epilogue: C/D frag layout col = lane&15, row = (lane>>4)*4 + reg
    float bj0[4], bj1[4];
#pragma unroll
    for (int j = 0; j < 4; ++j) {
        int col = bn + wc * 64 + j * 16 + l15;
        bj0[j] = bias0[col];
        if (BIASK == 3) bj1[j] = bias1[col];
    }
#pragma unroll
    for (int i = 0; i < 4; ++i) {
        int row0 = bm + wr * 64 + i * 16 + l4 * 4;
#pragma unroll
        for (int r = 0; r < 4; ++r) {
            int row = row0 + r;
            if (row < N_NODES) {
                float m0 = 1.f, m1 = 0.f;
                if (BIASK == 3) {
                    int bits = degmask[row] >> mshift;
                    m0 = (bits & 1) ? 1.f : 0.f;
                    m1 = (bits & 2) ? 1.f : 0.f;
                }
#pragma unroll
                for (int j = 0; j < 4; ++j) {
                    int col = bn + wc * 64 + j * 16 + l15;
                    float o = acc[i][j][r];
                    if (BIASK == 3) o += m0 * bj0[j] + m1 * bj1[j];
                    else            o += bj0[j];
                    u16* cp = C + (size_t)row * ldc + col;
                    if (ACCUM) o += b2f(*cp);
                    *cp = f2b(o);
                }
            }
        }
    }
}

// ---------------------------------------------------------------------------
// fused GRU cell + LayerNorm; one block per node; state f32 (in-place safe)
// ---------------------------------------------------------------------------
__global__ __launch_bounds__(256) void gru_ln_kernel(
    const u16* __restrict__ rz, const u16* __restrict__ nin,
    const u16* __restrict__ hn, const float* __restrict__ h,
    float* __restrict__ out,
    const float* __restrict__ gamma, const float* __restrict__ beta)
{
    int n = blockIdx.x;
    int j = threadIdx.x;
    size_t b2 = (size_t)n * 512;
    size_t b1 = (size_t)n * D;

    float r = 1.f / (1.f + __expf(-b2f(rz[b2 + j])));
    float z = 1.f / (1.f + __expf(-b2f(rz[b2 + 256 + j])));
    float xn = b2f(nin[b1 + j]) + r * b2f(hn[b1 + j]);
    float nn = 2.f / (1.f + __expf(-2.f * xn)) - 1.f;   // tanh
    float hv = h[b1 + j];
    float hnew = (1.f - z) * nn + z * hv;

    float s1 = hnew, s2 = hnew * hnew;
#pragma unroll
    for (int o = 32; o > 0; o >>= 1) {
        s1 += __shfl_down(s1, o);
        s2 += __shfl_down(s2, o);
    }
    __shared__ float red[8];
    int wv = j >> 6;
    if ((j & 63) == 0) { red[wv] = s1; red[4 + wv] = s2; }
    __syncthreads();
    float sum = red[0] + red[1] + red[2] + red[3];
    float ssq = red[4] + red[5] + red[6] + red[7];
    float mu = sum * (1.f / D);
    float var = ssq * (1.f / D) - mu * mu;
    float rstd = rsqrtf(var + 1e-5f);
    out[b1 + j] = (hnew - mu) * rstd * gamma[j] + beta[j];
}

__global__ __launch_bounds__(256) void wsfail_kernel(float* __restrict__ out, float val, int n)
{
    int i = blockIdx.x * 256 + threadIdx.x;
    if (i < n) out[i] = val;
}

// ---------------------------------------------------------------------------
extern "C" void kernel_launch(void* const* d_in, const int* in_sizes, int n_in,
                              void* d_out, int out_size, void* d_ws, size_t ws_size,
                              hipStream_t stream)
{
    const float* x    = (const float*)d_in[0];
    const int* se[4] = {(const int*)d_in[1], (const int*)d_in[5],
                        (const int*)d_in[9], (const int*)d_in[13]};
    const int* de[4] = {(const int*)d_in[2], (const int*)d_in[6],
                        (const int*)d_in[10], (const int*)d_in[14]};
    const float* We[4] = {(const float*)d_in[3], (const float*)d_in[7],
                          (const float*)d_in[11], (const float*)d_in[15]};
    const float* be[4] = {(const float*)d_in[4], (const float*)d_in[8],
                          (const float*)d_in[12], (const float*)d_in[16]};
    const float* W_ih = (const float*)d_in[17];
    const float* W_hh = (const float*)d_in[18];
    const float* b_ih = (const float*)d_in[19];
    const float* b_hh = (const float*)d_in[20];
    const float* gamma = (const float*)d_in[21];
    const float* beta  = (const float*)d_in[22];
    float* outf = (float*)d_out;          // f32 [N,D]; doubles as the h state

    // ---- workspace layout (bytes), total ~132.6 MB ----
    char* base = (char*)d_ws;
    size_t off = 0;
    u16* Hmean2 = (u16*)(base + off); off += (size_t)M_PAD * 512 * 2;  // 51.25 MB
    u16* rzb    = Hmean2;             // alias: Hmean2 dead before rz GEMM writes
    u16* aggb = (u16*)(base + off); off += (size_t)M_PAD * 256 * 2;    // 25.62 MB
    u16* ninb = (u16*)(base + off); off += (size_t)N_NODES * 256 * 2;  // 25.6 MB
    u16* hnb  = (u16*)(base + off); off += (size_t)N_NODES * 256 * 2;  // 25.6 MB
    int* rowptr = (int*)(base + off); off += (size_t)4 * (N_NODES + 1) * 4;
    u16* colb = (u16*)(base + off); off += (size_t)4 * E_EDGES * 2;
    unsigned char* degmask = (unsigned char*)(base + off); off += 50048;
    u16* Wrz_b  = (u16*)(base + off); off += 524288;
    u16* Bcat_b = (u16*)(base + off); off += 524288;
    u16* WnI_b  = (u16*)(base + off); off += 131072;
    u16* WnH_b  = (u16*)(base + off); off += 131072;
    float* brz  = (float*)(base + off); off += 2048;
    float* be4  = (float*)(base + off); off += 4096;

    if (ws_size < off) {
        wsfail_kernel<<<(out_size + 255) / 256, 256, 0, stream>>>(
            outf, (float)(ws_size >> 20), out_size);
        return;
    }

    // ---- once per launch: weight pack + CSR build + pad-row zeroing ----
    hipMemsetAsync(rowptr, 0, (size_t)4 * (N_NODES + 1) * 4, stream);
    hipMemsetAsync(Hmean2 + (size_t)N_NODES * 512, 0, (size_t)(M_PAD - N_NODES) * 512 * 2, stream);
    hipMemsetAsync(aggb + (size_t)N_NODES * 256, 0, (size_t)(M_PAD - N_NODES) * 256 * 2, stream);
    prep_kernel<<<1024, 256, 0, stream>>>(
        We[0], We[1], We[2], We[3], be[0], be[1], be[2], be[3],
        W_ih, W_hh, b_ih, b_hh, Wrz_b, Bcat_b, WnI_b, WnH_b, brz, be4);
    cnt_kernel<<<(4 * E_EDGES + 255) / 256, 256, 0, stream>>>(
        de[0], de[1], de[2], de[3], rowptr);
    scan_kernel<<<4, 1024, 0, stream>>>(rowptr);
    fill_csr_kernel<<<(4 * E_EDGES + 255) / 256, 256, 0, stream>>>(
        se[0], de[0], se[1], de[1], se[2], de[2], se[3], de[3], rowptr, colb);
    degmask_kernel<<<(N_NODES + 255) / 256, 256, 0, stream>>>(rowptr, degmask);

    const dim3 g2(2, 391), g4(4, 391);
    for (int step = 0; step < 3; ++step) {
        const float* hcur = (step == 0) ? x : outf;

        // agg (pair 0): Hmean2{e0,e1} @ Bcat0^T + masked biases -> aggb
        gather2_kernel<<<N_NODES / 2, 256, 0, stream>>>(hcur, rowptr, colb, Hmean2, 0);
        gemm_mfma<3, false><<<g2, 256, 0, stream>>>(
            Hmean2, 512, nullptr, 0, Bcat_b, aggb, 256,
            256, 512, 8, be4, be4 + 256, degmask, 0);
        // agg (pair 1): accumulate
        gather2_kernel<<<N_NODES / 2, 256, 0, stream>>>(hcur, rowptr, colb, Hmean2, 1);
        gemm_mfma<3, true><<<g2, 256, 0, stream>>>(
            Hmean2, 512, nullptr, 0, Bcat_b + 131072, aggb, 256,
            256, 512, 8, be4 + 512, be4 + 768, degmask, 2);

        // rz = [agg | h] @ Wrz^T + brz   (K=512: kt<4 bf16 aggb, kt>=4 f32 h)
        gemm_mfma<1, false><<<g4, 256, 0, stream>>>(
            aggb, 256, hcur, 256, Wrz_b, rzb, 512,
            512, 512, 4, brz, nullptr, nullptr, 0);
        // i_n = agg @ WnI^T + b_in
        gemm_mfma<1, false><<<g2, 256, 0, stream>>>(
            aggb, 256, nullptr, 0, WnI_b, ninb, 256,
            256, 256, 4, b_ih + 512, nullptr, nullptr, 0);
        // h_n = h @ WnH^T + b_hn   (all f32-staged)
        gemm_mfma<1, false><<<g2, 256, 0, stream>>>(
            nullptr, 0, hcur, 256, WnH_b, hnb, 256,
            256, 256, 0, b_hh + 512, nullptr, nullptr, 0);

        gru_ln_kernel<<<N_NODES, 256, 0, stream>>>(
            rzb, ninb, hnb, hcur, outf, gamma, beta);
    }
}

// Round 8
// 1263.392 us; speedup vs baseline: 11.9413x; 1.1043x over previous
//
#include <hip/hip_runtime.h>
#include <hip/hip_bf16.h>
#include <cstddef>

#define N_NODES 50000
#define E_EDGES 300000
#define D 256
#define M_PAD 50048           // 391 * 128

typedef unsigned short u16;
typedef __attribute__((ext_vector_type(8))) short bf16x8;   // 8 bf16 = 4 VGPRs
typedef __attribute__((ext_vector_type(4))) float f32x4;

__device__ __forceinline__ float b2f(u16 u) {
    return __uint_as_float(((unsigned)u) << 16);
}
__device__ __forceinline__ u16 f2b(float f) {
    __hip_bfloat16 h = __float2bfloat16(f);
    return *reinterpret_cast<u16*>(&h);
}
__device__ __forceinline__ void async16(const u16* g, u16* l) {
    __builtin_amdgcn_global_load_lds(
        (const __attribute__((address_space(1))) void*)g,
        (__attribute__((address_space(3))) void*)l, 16, 0, 0);
}

// ---------------------------------------------------------------------------
// prep: pack all weights to bf16 once.
//   Wrz_b[j][k]  = k<256 ? W_ih[j][k] : W_hh[j][k-256]         (512x512)
//   Bcat_b[p][j][el*256+kk] = W_{2p+el}[j][kk]                 (2 x 256 x 512)
//   WnI_b/WnH_b[j][k] = W_ih/W_hh[512+j][k]                    (256x256)
//   brz[j] = b_ih[j]+b_hh[j] (f32); be4[e][k] = b_e[k] (f32)
// ---------------------------------------------------------------------------
__global__ __launch_bounds__(256) void prep_kernel(
    const float* __restrict__ W0, const float* __restrict__ W1,
    const float* __restrict__ W2, const float* __restrict__ W3,
    const float* __restrict__ b0, const float* __restrict__ b1,
    const float* __restrict__ b2, const float* __restrict__ b3,
    const float* __restrict__ W_ih, const float* __restrict__ W_hh,
    const float* __restrict__ b_ih, const float* __restrict__ b_hh,
    u16* __restrict__ Wrz_b, u16* __restrict__ Bcat_b,
    u16* __restrict__ WnI_b, u16* __restrict__ WnH_b,
    float* __restrict__ brz, float* __restrict__ be4)
{
    int t = blockIdx.x * 256 + threadIdx.x;    // [0, 262144)
    {
        int j = t >> 9, k = t & 511;
        Wrz_b[t] = f2b(k < 256 ? W_ih[j * 256 + k] : W_hh[j * 256 + (k - 256)]);
    }
    {
        int p = t >> 17, rem = t & 131071;
        int j = rem >> 9, k = rem & 511;
        int e = p * 2 + (k >> 8), kk = k & 255;
        const float* W = (e == 0) ? W0 : (e == 1) ? W1 : (e == 2) ? W2 : W3;
        Bcat_b[t] = f2b(W[j * 256 + kk]);
    }
    if (t < 65536) {
        WnI_b[t] = f2b(W_ih[131072 + t]);
        WnH_b[t] = f2b(W_hh[131072 + t]);
    }
    if (t < 512) brz[t] = b_ih[t] + b_hh[t];
    if (t < 1024) {
        int e = t >> 8, k = t & 255;
        const float* b = (e == 0) ? b0 : (e == 1) ? b1 : (e == 2) ? b2 : b3;
        be4[t] = b[k];
    }
}

// ---------------------------------------------------------------------------
// x (f32) -> h_bf (bf16), once at step 0
// ---------------------------------------------------------------------------
__global__ __launch_bounds__(256) void xcvt_kernel(
    const float* __restrict__ x, u16* __restrict__ hb)
{
    int t = blockIdx.x * 256 + threadIdx.x;      // 4-elem slot
    float4 v = *reinterpret_cast<const float4*>(x + (size_t)t * 4);
    ushort4 o;
    o.x = f2b(v.x); o.y = f2b(v.y); o.z = f2b(v.z); o.w = f2b(v.w);
    *reinterpret_cast<ushort4*>(hb + (size_t)t * 4) = o;
}

// ---------------------------------------------------------------------------
// CSR build (cursor-free: rowptr doubles as the fill cursor)
// post-fill semantics: beg(n) = n ? rp[n-1] : 0 ; end(n) = rp[n]
// ---------------------------------------------------------------------------
__global__ __launch_bounds__(256) void cnt_kernel(
    const int* __restrict__ d0, const int* __restrict__ d1,
    const int* __restrict__ d2, const int* __restrict__ d3,
    int* __restrict__ rowptr)
{
    int i = blockIdx.x * 256 + threadIdx.x;
    if (i >= 4 * E_EDGES) return;
    int e = i / E_EDGES;
    int k = i - e * E_EDGES;
    const int* dp = (e == 0) ? d0 : (e == 1) ? d1 : (e == 2) ? d2 : d3;
    atomicAdd(&rowptr[e * (N_NODES + 1) + dp[k] + 1], 1);
}

__global__ __launch_bounds__(1024) void scan_kernel(int* __restrict__ rowptr)
{
    int e = blockIdx.x;
    int* rp = rowptr + e * (N_NODES + 1);
    __shared__ int s[1024];
    int t = threadIdx.x;
    int carry = 0;
    const int chunks = (N_NODES + 1 + 1023) / 1024;   // 49
    for (int c = 0; c < chunks; ++c) {
        int idx = c * 1024 + t;
        int v = (idx <= N_NODES) ? rp[idx] : 0;
        s[t] = v;
        __syncthreads();
#pragma unroll
        for (int o = 1; o < 1024; o <<= 1) {
            int u = (t >= o) ? s[t - o] : 0;
            __syncthreads();
            s[t] += u;
            __syncthreads();
        }
        if (idx <= N_NODES) rp[idx] = s[t] + carry;
        int tot = s[1023];
        __syncthreads();
        carry += tot;
    }
}

__global__ __launch_bounds__(256) void fill_csr_kernel(
    const int* __restrict__ s0, const int* __restrict__ d0,
    const int* __restrict__ s1, const int* __restrict__ d1,
    const int* __restrict__ s2, const int* __restrict__ d2,
    const int* __restrict__ s3, const int* __restrict__ d3,
    int* __restrict__ rowptr, u16* __restrict__ colb)
{
    int i = blockIdx.x * 256 + threadIdx.x;
    if (i >= 4 * E_EDGES) return;
    int e = i / E_EDGES;
    int k = i - e * E_EDGES;
    const int* sp = (e == 0) ? s0 : (e == 1) ? s1 : (e == 2) ? s2 : s3;
    const int* dp = (e == 0) ? d0 : (e == 1) ? d1 : (e == 2) ? d2 : d3;
    int dst = dp[k];
    int slot = atomicAdd(&rowptr[e * (N_NODES + 1) + dst], 1);
    colb[(size_t)e * E_EDGES + slot] = (u16)sp[k];
}

__global__ __launch_bounds__(256) void degmask_kernel(
    const int* __restrict__ rowptr, unsigned char* __restrict__ degmask)
{
    int n = blockIdx.x * 256 + threadIdx.x;
    if (n >= N_NODES) return;
    int m = 0;
#pragma unroll
    for (int e = 0; e < 4; ++e) {
        const int* rp = rowptr + e * (N_NODES + 1);
        int beg = n ? rp[n - 1] : 0;
        if (rp[n] > beg) m |= (1 << e);
    }
    degmask[n] = (unsigned char)m;
}

// ---------------------------------------------------------------------------
// gather2: Hmean2[n][el*256+c] = mean over in-edges(2*pair+el) of hb[src][c]
// 2 nodes per block; hb is bf16 state; output bf16
// ---------------------------------------------------------------------------
__global__ __launch_bounds__(256) void gather2_kernel(
    const u16* __restrict__ hb, const int* __restrict__ rowptr,
    const u16* __restrict__ colb, u16* __restrict__ Hmean2, int pair)
{
    int n = blockIdx.x * 2 + (threadIdx.x >> 7);
    int el = (threadIdx.x >> 6) & 1;
    int lane = threadIdx.x & 63;
    int e = pair * 2 + el;
    const int* rp = rowptr + e * (N_NODES + 1);
    int beg = n ? rp[n - 1] : 0;
    int end = rp[n];
    const u16* cb = colb + (size_t)e * E_EDGES;
    float ax = 0.f, ay = 0.f, az = 0.f, aw = 0.f;
    for (int j = beg; j < end; ++j) {
        int src = cb[j];
        ushort4 u = *reinterpret_cast<const ushort4*>(hb + (size_t)src * D + lane * 4);
        ax += b2f(u.x); ay += b2f(u.y); az += b2f(u.z); aw += b2f(u.w);
    }
    float s = (end > beg) ? 1.f / (float)(end - beg) : 0.f;
    ushort4 o;
    o.x = f2b(ax * s); o.y = f2b(ay * s); o.z = f2b(az * s); o.w = f2b(aw * s);
    *reinterpret_cast<ushort4*>(Hmean2 + (size_t)n * 512 + el * 256 + lane * 4) = o;
}

// ---------------------------------------------------------------------------
// MFMA GEMM: C[N_NODES,Ncol](bf16) = A[.,K] @ B[Ncol,K]^T + bias (+C if ACCUM)
// A: k-tile kt < KS from A0 (bf16, lda0); else from A1 (bf16, lda1).
// BIASK 1: bias0[col].  BIASK 3: per-row etype-pair masked bias0/bias1.
// 128x128 tile, BK=64, 256 thr = 4 waves (2x2), 64x64/wave, mfma 16x16x32 bf16.
// LDS: [128 rows][8 chunks of 16B], chunk XOR-swizzled by (row&7); staged via
// global_load_lds w/ pre-swizzled source (both-sides rule).
// ---------------------------------------------------------------------------
template <int BIASK, bool ACCUM>
__global__ __launch_bounds__(256) void gemm_mfma(
    const u16* __restrict__ A0, int lda0,
    const u16* __restrict__ A1, int lda1,
    const u16* __restrict__ Bw, u16* __restrict__ C, int ldc,
    int Ncol, int K, int KS,
    const float* __restrict__ bias0, const float* __restrict__ bias1,
    const unsigned char* __restrict__ degmask, int mshift)
{
    __shared__ u16 As[8192];    // 128 x 64 bf16 (16 KB)
    __shared__ u16 Bs2[8192];
    const int bm = blockIdx.y * 128;
    const int bn = blockIdx.x * 128;
    const int tid = threadIdx.x;
    const int lane = tid & 63;
    const int wid = tid >> 6;
    const int wr = wid >> 1;
    const int wc = wid & 1;
    const int l15 = lane & 15;
    const int l4 = lane >> 4;

    int srow[4], schk[4];
#pragma unroll
    for (int i = 0; i < 4; ++i) {
        int q = (wid * 4 + i) * 64 + lane;
        srow[i] = q >> 3;                       // tile row / B row
        schk[i] = (q & 7) ^ (srow[i] & 7);      // source 16B chunk (pre-swizzle)
    }

    f32x4 acc[4][4];
#pragma unroll
    for (int i = 0; i < 4; ++i)
#pragma unroll
        for (int j = 0; j < 4; ++j)
            acc[i][j] = (f32x4){0.f, 0.f, 0.f, 0.f};

    const int nkt = K >> 6;
    for (int kt = 0; kt < nkt; ++kt) {
        const u16* Ab = (kt < KS) ? A0 + (size_t)kt * 64
                                  : A1 + (size_t)(kt - KS) * 64;
        const int lda = (kt < KS) ? lda0 : lda1;
#pragma unroll
        for (int i = 0; i < 4; ++i)
            async16(Ab + (size_t)(bm + srow[i]) * lda + schk[i] * 8,
                    &As[(wid * 4 + i) * 512]);
#pragma unroll
        for (int i = 0; i < 4; ++i)
            async16(Bw + (size_t)(bn + srow[i]) * K + kt * 64 + schk[i] * 8,
                    &Bs2[(wid * 4 + i) * 512]);
        __syncthreads();

#pragma unroll
        for (int kk = 0; kk < 2; ++kk) {
            bf16x8 a[4], b[4];
#pragma unroll
            for (int i = 0; i < 4; ++i) {
                int ar = wr * 64 + i * 16 + l15;
                a[i] = *reinterpret_cast<const bf16x8*>(
                    &As[ar * 64 + (((kk * 4 + l4) ^ (ar & 7)) << 3)]);
                int bc = wc * 64 + i * 16 + l15;
                b[i] = *reinterpret_cast<const bf16x8*>(
                    &Bs2[bc * 64 + (((kk * 4 + l4) ^ (bc & 7)) << 3)]);
            }
#pragma unroll
            for (int i = 0; i < 4; ++i)
#pragma unroll
                for (int j = 0; j < 4; ++j)
                    acc[i][j] = __builtin_amdgcn_mfma_f32_16x16x32_bf16(
                        a[i], b[j], acc[i][j], 0, 0, 0);
        }
        __syncthreads();
    }

    // epilogue: C/D frag layout col = lane&15, row = (lane>>4)*4 + reg
    float bj0[4], bj1[4];
#pragma unroll
    for (int j = 0; j < 4; ++j) {
        int col = bn + wc * 64 + j * 16 + l15;
        bj0[j] = bias0[col];
        if (BIASK == 3) bj1[j] = bias1[col];
    }
#pragma unroll
    for (int i = 0; i < 4; ++i) {
        int row0 = bm + wr * 64 + i * 16 + l4 * 4;
#pragma unroll
        for (int r = 0; r < 4; ++r) {
            int row = row0 + r;
            if (row < N_NODES) {
                float m0 = 1.f, m1 = 0.f;
                if (BIASK == 3) {
                    int bits = degmask[row] >> mshift;
                    m0 = (bits & 1) ? 1.f : 0.f;
                    m1 = (bits & 2) ? 1.f : 0.f;
                }
#pragma unroll
                for (int j = 0; j < 4; ++j) {
                    int col = bn + wc * 64 + j * 16 + l15;
                    float o = acc[i][j][r];
                    if (BIASK == 3) o += m0 * bj0[j] + m1 * bj1[j];
                    else            o += bj0[j];
                    u16* cp = C + (size_t)row * ldc + col;
                    if (ACCUM) o += b2f(*cp);
                    *cp = f2b(o);
                }
            }
        }
    }
}

// ---------------------------------------------------------------------------
// fused GRU cell + LayerNorm; one block per node; state h_bf bf16.
// OUTM 0: write bf16 state (h_bf, in-place safe). OUTM 1: write f32 d_out.
// ---------------------------------------------------------------------------
template <int OUTM>
__global__ __launch_bounds__(256) void gru_ln_kernel(
    const u16* __restrict__ rz, const u16* __restrict__ nin,
    const u16* __restrict__ hn, const u16* __restrict__ hb,
    void* __restrict__ outv,
    const float* __restrict__ gamma, const float* __restrict__ beta)
{
    int n = blockIdx.x;
    int j = threadIdx.x;
    size_t b2 = (size_t)n * 512;
    size_t b1 = (size_t)n * D;

    float r = 1.f / (1.f + __expf(-b2f(rz[b2 + j])));
    float z = 1.f / (1.f + __expf(-b2f(rz[b2 + 256 + j])));
    float xn = b2f(nin[b1 + j]) + r * b2f(hn[b1 + j]);
    float nn = 2.f / (1.f + __expf(-2.f * xn)) - 1.f;   // tanh
    float hv = b2f(hb[b1 + j]);
    float hnew = (1.f - z) * nn + z * hv;

    float s1 = hnew, s2 = hnew * hnew;
#pragma unroll
    for (int o = 32; o > 0; o >>= 1) {
        s1 += __shfl_down(s1, o);
        s2 += __shfl_down(s2, o);
    }
    __shared__ float red[8];
    int wv = j >> 6;
    if ((j & 63) == 0) { red[wv] = s1; red[4 + wv] = s2; }
    __syncthreads();
    float sum = red[0] + red[1] + red[2] + red[3];
    float ssq = red[4] + red[5] + red[6] + red[7];
    float mu = sum * (1.f / D);
    float var = ssq * (1.f / D) - mu * mu;
    float rstd = rsqrtf(var + 1e-5f);
    float res = (hnew - mu) * rstd * gamma[j] + beta[j];
    if (OUTM == 0) ((u16*)outv)[b1 + j] = f2b(res);
    else           ((float*)outv)[b1 + j] = res;
}

__global__ __launch_bounds__(256) void wsfail_kernel(float* __restrict__ out, float val, int n)
{
    int i = blockIdx.x * 256 + threadIdx.x;
    if (i < n) out[i] = val;
}

// ---------------------------------------------------------------------------
extern "C" void kernel_launch(void* const* d_in, const int* in_sizes, int n_in,
                              void* d_out, int out_size, void* d_ws, size_t ws_size,
                              hipStream_t stream)
{
    const float* x    = (const float*)d_in[0];
    const int* se[4] = {(const int*)d_in[1], (const int*)d_in[5],
                        (const int*)d_in[9], (const int*)d_in[13]};
    const int* de[4] = {(const int*)d_in[2], (const int*)d_in[6],
                        (const int*)d_in[10], (const int*)d_in[14]};
    const float* We[4] = {(const float*)d_in[3], (const float*)d_in[7],
                          (const float*)d_in[11], (const float*)d_in[15]};
    const float* be[4] = {(const float*)d_in[4], (const float*)d_in[8],
                          (const float*)d_in[12], (const float*)d_in[16]};
    const float* W_ih = (const float*)d_in[17];
    const float* W_hh = (const float*)d_in[18];
    const float* b_ih = (const float*)d_in[19];
    const float* b_hh = (const float*)d_in[20];
    const float* gamma = (const float*)d_in[21];
    const float* beta  = (const float*)d_in[22];
    float* outf = (float*)d_out;          // f32 [N,D], written at final step only

    // ---- workspace layout (bytes), total ~132.7 MB ----
    char* base = (char*)d_ws;
    size_t off = 0;
    u16* Hmean2 = (u16*)(base + off); off += (size_t)M_PAD * 512 * 2;  // 51.25 MB
    u16* rzb    = Hmean2;             // alias: Hmean2 dead before rz GEMM writes
    u16* aggb = (u16*)(base + off); off += (size_t)M_PAD * 256 * 2;    // 25.62 MB
    u16* hnb  = aggb;                 // alias: aggb dead before hn GEMM writes
    u16* ninb = (u16*)(base + off); off += (size_t)N_NODES * 256 * 2;  // 25.6 MB
    u16* h_bf = (u16*)(base + off); off += (size_t)M_PAD * 256 * 2;    // 25.62 MB
    int* rowptr = (int*)(base + off); off += (size_t)4 * (N_NODES + 1) * 4;
    u16* colb = (u16*)(base + off); off += (size_t)4 * E_EDGES * 2;
    unsigned char* degmask = (unsigned char*)(base + off); off += 50048;
    u16* Wrz_b  = (u16*)(base + off); off += 524288;
    u16* Bcat_b = (u16*)(base + off); off += 524288;
    u16* WnI_b  = (u16*)(base + off); off += 131072;
    u16* WnH_b  = (u16*)(base + off); off += 131072;
    float* brz  = (float*)(base + off); off += 2048;
    float* be4  = (float*)(base + off); off += 4096;

    if (ws_size < off) {
        wsfail_kernel<<<(out_size + 255) / 256, 256, 0, stream>>>(
            outf, (float)(ws_size >> 20), out_size);
        return;
    }

    // ---- once per launch: weight pack + CSR build + pad-row zeroing ----
    hipMemsetAsync(rowptr, 0, (size_t)4 * (N_NODES + 1) * 4, stream);
    hipMemsetAsync(Hmean2 + (size_t)N_NODES * 512, 0, (size_t)(M_PAD - N_NODES) * 512 * 2, stream);
    hipMemsetAsync(aggb + (size_t)N_NODES * 256, 0, (size_t)(M_PAD - N_NODES) * 256 * 2, stream);
    hipMemsetAsync(h_bf + (size_t)N_NODES * 256, 0, (size_t)(M_PAD - N_NODES) * 256 * 2, stream);
    prep_kernel<<<1024, 256, 0, stream>>>(
        We[0], We[1], We[2], We[3], be[0], be[1], be[2], be[3],
        W_ih, W_hh, b_ih, b_hh, Wrz_b, Bcat_b, WnI_b, WnH_b, brz, be4);
    xcvt_kernel<<<N_NODES * D / 4 / 256, 256, 0, stream>>>(x, h_bf);
    cnt_kernel<<<(4 * E_EDGES + 255) / 256, 256, 0, stream>>>(
        de[0], de[1], de[2], de[3], rowptr);
    scan_kernel<<<4, 1024, 0, stream>>>(rowptr);
    fill_csr_kernel<<<(4 * E_EDGES + 255) / 256, 256, 0, stream>>>(
        se[0], de[0], se[1], de[1], se[2], de[2], se[3], de[3], rowptr, colb);
    degmask_kernel<<<(N_NODES + 255) / 256, 256, 0, stream>>>(rowptr, degmask);

    const dim3 g2(2, 391), g4(4, 391);
    for (int step = 0; step < 3; ++step) {
        // agg (pair 0): Hmean2{e0,e1} @ Bcat0^T + masked biases -> aggb
        gather2_kernel<<<N_NODES / 2, 256, 0, stream>>>(h_bf, rowptr, colb, Hmean2, 0);
        gemm_mfma<3, false><<<g2, 256, 0, stream>>>(
            Hmean2, 512, nullptr, 0, Bcat_b, aggb, 256,
            256, 512, 8, be4, be4 + 256, degmask, 0);
        // agg (pair 1): accumulate
        gather2_kernel<<<N_NODES / 2, 256, 0, stream>>>(h_bf, rowptr, colb, Hmean2, 1);
        gemm_mfma<3, true><<<g2, 256, 0, stream>>>(
            Hmean2, 512, nullptr, 0, Bcat_b + 131072, aggb, 256,
            256, 512, 8, be4 + 512, be4 + 768, degmask, 2);

        // rz = [agg | h] @ Wrz^T + brz   (K=512: kt<4 aggb, kt>=4 h_bf)
        gemm_mfma<1, false><<<g4, 256, 0, stream>>>(
            aggb, 256, h_bf, 256, Wrz_b, rzb, 512,
            512, 512, 4, brz, nullptr, nullptr, 0);
        // i_n = agg @ WnI^T + b_in
        gemm_mfma<1, false><<<g2, 256, 0, stream>>>(
            aggb, 256, nullptr, 0, WnI_b, ninb, 256,
            256, 256, 4, b_ih + 512, nullptr, nullptr, 0);
        // h_n = h @ WnH^T + b_hn   (writes hnb = aggb alias; aggb dead now)
        gemm_mfma<1, false><<<g2, 256, 0, stream>>>(
            h_bf, 256, nullptr, 0, WnH_b, hnb, 256,
            256, 256, 4, b_hh + 512, nullptr, nullptr, 0);

        // steps 0,1 -> h_bf (bf16, in-place safe); step 2 -> d_out (f32)
        if (step < 2)
            gru_ln_kernel<0><<<N_NODES, 256, 0, stream>>>(
                rzb, ninb, hnb, h_bf, h_bf, gamma, beta);
        else
            gru_ln_kernel<1><<<N_NODES, 256, 0, stream>>>(
                rzb, ninb, hnb, h_bf, outf, gamma, beta);
    }
}

// Round 9
// 1130.251 us; speedup vs baseline: 13.3479x; 1.1178x over previous
//
#include <hip/hip_runtime.h>
#include <hip/hip_bf16.h>
#include <cstddef>

#define N_NODES 50000
#define E_EDGES 300000
#define D 256
#define M_PAD 50048           // 391 * 128
#define SCHUNKS 196           // ceil(50001/256)

typedef unsigned short u16;
typedef __attribute__((ext_vector_type(8))) short bf16x8;   // 8 bf16 = 4 VGPRs
typedef __attribute__((ext_vector_type(4))) float f32x4;

__device__ __forceinline__ float b2f(u16 u) {
    return __uint_as_float(((unsigned)u) << 16);
}
__device__ __forceinline__ u16 f2b(float f) {
    __hip_bfloat16 h = __float2bfloat16(f);
    return *reinterpret_cast<u16*>(&h);
}
__device__ __forceinline__ void async16(const u16* g, u16* l) {
    __builtin_amdgcn_global_load_lds(
        (const __attribute__((address_space(1))) void*)g,
        (__attribute__((address_space(3))) void*)l, 16, 0, 0);
}

// ---------------------------------------------------------------------------
// prep: pack all weights to bf16 once.
// ---------------------------------------------------------------------------
__global__ __launch_bounds__(256) void prep_kernel(
    const float* __restrict__ W0, const float* __restrict__ W1,
    const float* __restrict__ W2, const float* __restrict__ W3,
    const float* __restrict__ b0, const float* __restrict__ b1,
    const float* __restrict__ b2, const float* __restrict__ b3,
    const float* __restrict__ W_ih, const float* __restrict__ W_hh,
    const float* __restrict__ b_ih, const float* __restrict__ b_hh,
    u16* __restrict__ Wrz_b, u16* __restrict__ Bcat_b,
    u16* __restrict__ WnI_b, u16* __restrict__ WnH_b,
    float* __restrict__ brz, float* __restrict__ be4)
{
    int t = blockIdx.x * 256 + threadIdx.x;    // [0, 262144)
    {
        int j = t >> 9, k = t & 511;
        Wrz_b[t] = f2b(k < 256 ? W_ih[j * 256 + k] : W_hh[j * 256 + (k - 256)]);
    }
    {
        int p = t >> 17, rem = t & 131071;
        int j = rem >> 9, k = rem & 511;
        int e = p * 2 + (k >> 8), kk = k & 255;
        const float* W = (e == 0) ? W0 : (e == 1) ? W1 : (e == 2) ? W2 : W3;
        Bcat_b[t] = f2b(W[j * 256 + kk]);
    }
    if (t < 65536) {
        WnI_b[t] = f2b(W_ih[131072 + t]);
        WnH_b[t] = f2b(W_hh[131072 + t]);
    }
    if (t < 512) brz[t] = b_ih[t] + b_hh[t];
    if (t < 1024) {
        int e = t >> 8, k = t & 255;
        const float* b = (e == 0) ? b0 : (e == 1) ? b1 : (e == 2) ? b2 : b3;
        be4[t] = b[k];
    }
}

__global__ __launch_bounds__(256) void xcvt_kernel(
    const float* __restrict__ x, u16* __restrict__ hb)
{
    int t = blockIdx.x * 256 + threadIdx.x;      // 4-elem slot
    float4 v = *reinterpret_cast<const float4*>(x + (size_t)t * 4);
    ushort4 o;
    o.x = f2b(v.x); o.y = f2b(v.y); o.z = f2b(v.z); o.w = f2b(v.w);
    *reinterpret_cast<ushort4*>(hb + (size_t)t * 4) = o;
}

// ---------------------------------------------------------------------------
// CSR build. counts at rp[e][dst+1]; after scan rp[n] = beg(n); fill uses
// rp as cursor so post-fill rp[n] = end(n); beg(n) = n ? rp[n-1] : 0.
// ---------------------------------------------------------------------------
__global__ __launch_bounds__(256) void cnt_kernel(
    const int* __restrict__ d0, const int* __restrict__ d1,
    const int* __restrict__ d2, const int* __restrict__ d3,
    int* __restrict__ rowptr)
{
    int i = blockIdx.x * 256 + threadIdx.x;
    if (i >= 4 * E_EDGES) return;
    int e = i / E_EDGES;
    int k = i - e * E_EDGES;
    const int* dp = (e == 0) ? d0 : (e == 1) ? d1 : (e == 2) ? d2 : d3;
    atomicAdd(&rowptr[e * (N_NODES + 1) + dp[k] + 1], 1);
}

// hierarchical inclusive scan: per-256 block scan + block sums
__global__ __launch_bounds__(256) void scan1_kernel(
    int* __restrict__ rowptr, int* __restrict__ bsum)
{
    int e = blockIdx.y;
    int blk = blockIdx.x;
    int t = threadIdx.x;
    int idx = blk * 256 + t;
    int* rp = rowptr + e * (N_NODES + 1);
    int v = (idx <= N_NODES) ? rp[idx] : 0;
    __shared__ int s[256];
    s[t] = v;
    __syncthreads();
    for (int o = 1; o < 256; o <<= 1) {
        int u = (t >= o) ? s[t - o] : 0;
        __syncthreads();
        s[t] += u;
        __syncthreads();
    }
    if (idx <= N_NODES) rp[idx] = s[t];
    if (t == 255) bsum[e * SCHUNKS + blk] = s[255];
}

__global__ __launch_bounds__(256) void scan2_kernel(int* __restrict__ bsum)
{
    int e = blockIdx.x;
    int t = threadIdx.x;
    int v = (t < SCHUNKS) ? bsum[e * SCHUNKS + t] : 0;
    __shared__ int s[256];
    s[t] = v;
    __syncthreads();
    for (int o = 1; o < 256; o <<= 1) {
        int u = (t >= o) ? s[t - o] : 0;
        __syncthreads();
        s[t] += u;
        __syncthreads();
    }
    if (t < SCHUNKS) bsum[e * SCHUNKS + t] = s[t];
}

__global__ __launch_bounds__(256) void scan3_kernel(
    int* __restrict__ rowptr, const int* __restrict__ bsum)
{
    int e = blockIdx.y;
    int blk = blockIdx.x;
    if (blk == 0) return;
    int idx = blk * 256 + threadIdx.x;
    if (idx > N_NODES) return;
    rowptr[e * (N_NODES + 1) + idx] += bsum[e * SCHUNKS + blk - 1];
}

__global__ __launch_bounds__(256) void fill_csr_kernel(
    const int* __restrict__ s0, const int* __restrict__ d0,
    const int* __restrict__ s1, const int* __restrict__ d1,
    const int* __restrict__ s2, const int* __restrict__ d2,
    const int* __restrict__ s3, const int* __restrict__ d3,
    int* __restrict__ rowptr, u16* __restrict__ colb)
{
    int i = blockIdx.x * 256 + threadIdx.x;
    if (i >= 4 * E_EDGES) return;
    int e = i / E_EDGES;
    int k = i - e * E_EDGES;
    const int* sp = (e == 0) ? s0 : (e == 1) ? s1 : (e == 2) ? s2 : s3;
    const int* dp = (e == 0) ? d0 : (e == 1) ? d1 : (e == 2) ? d2 : d3;
    int dst = dp[k];
    int slot = atomicAdd(&rowptr[e * (N_NODES + 1) + dst], 1);
    colb[(size_t)e * E_EDGES + slot] = (u16)sp[k];
}

__global__ __launch_bounds__(256) void degmask_kernel(
    const int* __restrict__ rowptr, unsigned char* __restrict__ degmask)
{
    int n = blockIdx.x * 256 + threadIdx.x;
    if (n >= N_NODES) return;
    int m = 0;
#pragma unroll
    for (int e = 0; e < 4; ++e) {
        const int* rp = rowptr + e * (N_NODES + 1);
        int beg = n ? rp[n - 1] : 0;
        if (rp[n] > beg) m |= (1 << e);
    }
    degmask[n] = (unsigned char)m;
}

// ---------------------------------------------------------------------------
// gather2: Hmean2[n][el*256+c] = mean over in-edges(2*pair+el) of hb[src][c]
// ---------------------------------------------------------------------------
__global__ __launch_bounds__(256) void gather2_kernel(
    const u16* __restrict__ hb, const int* __restrict__ rowptr,
    const u16* __restrict__ colb, u16* __restrict__ Hmean2, int pair)
{
    int n = blockIdx.x * 2 + (threadIdx.x >> 7);
    int el = (threadIdx.x >> 6) & 1;
    int lane = threadIdx.x & 63;
    int e = pair * 2 + el;
    const int* rp = rowptr + e * (N_NODES + 1);
    int beg = n ? rp[n - 1] : 0;
    int end = rp[n];
    const u16* cb = colb + (size_t)e * E_EDGES;
    float ax = 0.f, ay = 0.f, az = 0.f, aw = 0.f;
    for (int j = beg; j < end; ++j) {
        int src = cb[j];
        ushort4 u = *reinterpret_cast<const ushort4*>(hb + (size_t)src * D + lane * 4);
        ax += b2f(u.x); ay += b2f(u.y); az += b2f(u.z); aw += b2f(u.w);
    }
    float s = (end > beg) ? 1.f / (float)(end - beg) : 0.f;
    ushort4 o;
    o.x = f2b(ax * s); o.y = f2b(ay * s); o.z = f2b(az * s); o.w = f2b(aw * s);
    *reinterpret_cast<ushort4*>(Hmean2 + (size_t)n * 512 + el * 256 + lane * 4) = o;
}

// ---------------------------------------------------------------------------
// MFMA GEMM, 128x128 tile, BK=64, XOR-swizzled LDS, global_load_lds staging.
// XCD-aware bijective block swizzle (T1/m204): co-locates col-blocks of one
// row-panel on the same XCD so the A-panel is fetched into that L2 once.
// ---------------------------------------------------------------------------
template <int BIASK, bool ACCUM>
__global__ __launch_bounds__(256) void gemm_mfma(
    const u16* __restrict__ A0, int lda0,
    const u16* __restrict__ A1, int lda1,
    const u16* __restrict__ Bw, u16* __restrict__ C, int ldc,
    int Ncol, int K, int KS,
    const float* __restrict__ bias0, const float* __restrict__ bias1,
    const unsigned char* __restrict__ degmask, int mshift)
{
    __shared__ u16 As[8192];    // 128 x 64 bf16 (16 KB)
    __shared__ u16 Bs2[8192];

    // bijective XCD swizzle: lin (hw dispatch id, round-robin across 8 XCDs)
    // -> wg (work id) such that each XCD gets a contiguous chunk of work.
    const int gx = gridDim.x;
    const int nwg = gx * gridDim.y;
    const int lin = blockIdx.y * gx + blockIdx.x;
    const int q = nwg >> 3, r = nwg & 7;
    const int xcd = lin & 7, pos = lin >> 3;
    const int wg = (xcd < r) ? xcd * (q + 1) + pos
                             : r * (q + 1) + (xcd - r) * q + pos;
    const int by = wg / gx;
    const int bx = wg - by * gx;
    const int bm = by * 128;
    const int bn = bx * 128;

    const int tid = threadIdx.x;
    const int lane = tid & 63;
    const int wid = tid >> 6;
    const int wr = wid >> 1;
    const int wc = wid & 1;
    const int l15 = lane & 15;
    const int l4 = lane >> 4;

    int srow[4], schk[4];
#pragma unroll
    for (int i = 0; i < 4; ++i) {
        int qq = (wid * 4 + i) * 64 + lane;
        srow[i] = qq >> 3;                      // tile row / B row
        schk[i] = (qq & 7) ^ (srow[i] & 7);     // source 16B chunk (pre-swizzle)
    }

    f32x4 acc[4][4];
#pragma unroll
    for (int i = 0; i < 4; ++i)
#pragma unroll
        for (int j = 0; j < 4; ++j)
            acc[i][j] = (f32x4){0.f, 0.f, 0.f, 0.f};

    const int nkt = K >> 6;
    for (int kt = 0; kt < nkt; ++kt) {
        const u16* Ab = (kt < KS) ? A0 + (size_t)kt * 64
                                  : A1 + (size_t)(kt - KS) * 64;
        const int lda = (kt < KS) ? lda0 : lda1;
#pragma unroll
        for (int i = 0; i < 4; ++i)
            async16(Ab + (size_t)(bm + srow[i]) * lda + schk[i] * 8,
                    &As[(wid * 4 + i) * 512]);
#pragma unroll
        for (int i = 0; i < 4; ++i)
            async16(Bw + (size_t)(bn + srow[i]) * K + kt * 64 + schk[i] * 8,
                    &Bs2[(wid * 4 + i) * 512]);
        __syncthreads();

#pragma unroll
        for (int kk = 0; kk < 2; ++kk) {
            bf16x8 a[4], b[4];
#pragma unroll
            for (int i = 0; i < 4; ++i) {
                int ar = wr * 64 + i * 16 + l15;
                a[i] = *reinterpret_cast<const bf16x8*>(
                    &As[ar * 64 + (((kk * 4 + l4) ^ (ar & 7)) << 3)]);
                int bc = wc * 64 + i * 16 + l15;
                b[i] = *reinterpret_cast<const bf16x8*>(
                    &Bs2[bc * 64 + (((kk * 4 + l4) ^ (bc & 7)) << 3)]);
            }
#pragma unroll
            for (int i = 0; i < 4; ++i)
#pragma unroll
                for (int j = 0; j < 4; ++j)
                    acc[i][j] = __builtin_amdgcn_mfma_f32_16x16x32_bf16(
                        a[i], b[j], acc[i][j], 0, 0, 0);
        }
        __syncthreads();
    }

    // epilogue: C/D frag layout col = lane&15, row = (lane>>4)*4 + reg
    float bj0[4], bj1[4];
#pragma unroll
    for (int j = 0; j < 4; ++j) {
        int col = bn + wc * 64 + j * 16 + l15;
        bj0[j] = bias0[col];
        if (BIASK == 3) bj1[j] = bias1[col];
    }
#pragma unroll
    for (int i = 0; i < 4; ++i) {
        int row0 = bm + wr * 64 + i * 16 + l4 * 4;
#pragma unroll
        for (int r2 = 0; r2 < 4; ++r2) {
            int row = row0 + r2;
            if (row < N_NODES) {
                float m0 = 1.f, m1 = 0.f;
                if (BIASK == 3) {
                    int bits = degmask[row] >> mshift;
                    m0 = (bits & 1) ? 1.f : 0.f;
                    m1 = (bits & 2) ? 1.f : 0.f;
                }
#pragma unroll
                for (int j = 0; j < 4; ++j) {
                    int col = bn + wc * 64 + j * 16 + l15;
                    float o = acc[i][j][r2];
                    if (BIASK == 3) o += m0 * bj0[j] + m1 * bj1[j];
                    else            o += bj0[j];
                    u16* cp = C + (size_t)row * ldc + col;
                    if (ACCUM) o += b2f(*cp);
                    *cp = f2b(o);
                }
            }
        }
    }
}

// ---------------------------------------------------------------------------
// fused GRU cell + LayerNorm: one WAVE per node, ushort4 per lane (vectorized),
// shuffle-only reduction. OUTM 0: bf16 state in-place; OUTM 1: f32 d_out.
// ---------------------------------------------------------------------------
template <int OUTM>
__global__ __launch_bounds__(256) void gru_ln_kernel(
    const u16* __restrict__ rz, const u16* __restrict__ nin,
    const u16* __restrict__ hn, const u16* __restrict__ hb,
    void* __restrict__ outv,
    const float* __restrict__ gamma, const float* __restrict__ beta)
{
    int w = threadIdx.x >> 6;
    int l = threadIdx.x & 63;
    int n = blockIdx.x * 4 + w;
    size_t b2 = (size_t)n * 512;
    size_t b1 = (size_t)n * D;

    u16 ra[4], za[4], na[4], ha[4], va[4];
    *reinterpret_cast<ushort4*>(ra) = *reinterpret_cast<const ushort4*>(rz + b2 + l * 4);
    *reinterpret_cast<ushort4*>(za) = *reinterpret_cast<const ushort4*>(rz + b2 + 256 + l * 4);
    *reinterpret_cast<ushort4*>(na) = *reinterpret_cast<const ushort4*>(nin + b1 + l * 4);
    *reinterpret_cast<ushort4*>(ha) = *reinterpret_cast<const ushort4*>(hn + b1 + l * 4);
    *reinterpret_cast<ushort4*>(va) = *reinterpret_cast<const ushort4*>(hb + b1 + l * 4);

    float hnew[4];
    float s1 = 0.f, s2 = 0.f;
#pragma unroll
    for (int c = 0; c < 4; ++c) {
        float r = 1.f / (1.f + __expf(-b2f(ra[c])));
        float z = 1.f / (1.f + __expf(-b2f(za[c])));
        float xn = b2f(na[c]) + r * b2f(ha[c]);
        float nn = 2.f / (1.f + __expf(-2.f * xn)) - 1.f;   // tanh
        hnew[c] = (1.f - z) * nn + z * b2f(va[c]);
        s1 += hnew[c];
        s2 += hnew[c] * hnew[c];
    }
#pragma unroll
    for (int o = 32; o > 0; o >>= 1) {
        s1 += __shfl_down(s1, o);
        s2 += __shfl_down(s2, o);
    }
    float sum = __shfl(s1, 0);
    float ssq = __shfl(s2, 0);
    float mu = sum * (1.f / D);
    float var = ssq * (1.f / D) - mu * mu;
    float rstd = rsqrtf(var + 1e-5f);

    float4 g = *reinterpret_cast<const float4*>(gamma + l * 4);
    float4 bt = *reinterpret_cast<const float4*>(beta + l * 4);
    float res[4];
    res[0] = (hnew[0] - mu) * rstd * g.x + bt.x;
    res[1] = (hnew[1] - mu) * rstd * g.y + bt.y;
    res[2] = (hnew[2] - mu) * rstd * g.z + bt.z;
    res[3] = (hnew[3] - mu) * rstd * g.w + bt.w;

    if (OUTM == 0) {
        ushort4 o;
        o.x = f2b(res[0]); o.y = f2b(res[1]); o.z = f2b(res[2]); o.w = f2b(res[3]);
        *reinterpret_cast<ushort4*>((u16*)outv + b1 + l * 4) = o;
    } else {
        *reinterpret_cast<float4*>((float*)outv + b1 + l * 4) =
            make_float4(res[0], res[1], res[2], res[3]);
    }
}

__global__ __launch_bounds__(256) void wsfail_kernel(float* __restrict__ out, float val, int n)
{
    int i = blockIdx.x * 256 + threadIdx.x;
    if (i < n) out[i] = val;
}

// ---------------------------------------------------------------------------
extern "C" void kernel_launch(void* const* d_in, const int* in_sizes, int n_in,
                              void* d_out, int out_size, void* d_ws, size_t ws_size,
                              hipStream_t stream)
{
    const float* x    = (const float*)d_in[0];
    const int* se[4] = {(const int*)d_in[1], (const int*)d_in[5],
                        (const int*)d_in[9], (const int*)d_in[13]};
    const int* de[4] = {(const int*)d_in[2], (const int*)d_in[6],
                        (const int*)d_in[10], (const int*)d_in[14]};
    const float* We[4] = {(const float*)d_in[3], (const float*)d_in[7],
                          (const float*)d_in[11], (const float*)d_in[15]};
    const float* be[4] = {(const float*)d_in[4], (const float*)d_in[8],
                          (const float*)d_in[12], (const float*)d_in[16]};
    const float* W_ih = (const float*)d_in[17];
    const float* W_hh = (const float*)d_in[18];
    const float* b_ih = (const float*)d_in[19];
    const float* b_hh = (const float*)d_in[20];
    const float* gamma = (const float*)d_in[21];
    const float* beta  = (const float*)d_in[22];
    float* outf = (float*)d_out;          // f32 [N,D], written at final step only

    // ---- workspace layout (bytes), total ~132.7 MB ----
    char* base = (char*)d_ws;
    size_t off = 0;
    u16* Hmean2 = (u16*)(base + off); off += (size_t)M_PAD * 512 * 2;  // 51.25 MB
    u16* rzb    = Hmean2;             // alias: Hmean2 dead before rz GEMM writes
    u16* aggb = (u16*)(base + off); off += (size_t)M_PAD * 256 * 2;    // 25.62 MB
    u16* hnb  = aggb;                 // alias: aggb dead before hn GEMM writes
    u16* ninb = (u16*)(base + off); off += (size_t)N_NODES * 256 * 2;  // 25.6 MB
    u16* h_bf = (u16*)(base + off); off += (size_t)M_PAD * 256 * 2;    // 25.62 MB
    int* rowptr = (int*)(base + off); off += (size_t)4 * (N_NODES + 1) * 4;
    u16* colb = (u16*)(base + off); off += (size_t)4 * E_EDGES * 2;
    unsigned char* degmask = (unsigned char*)(base + off); off += 50048;
    int* bsum = (int*)(base + off); off += (size_t)4 * SCHUNKS * 4;
    u16* Wrz_b  = (u16*)(base + off); off += 524288;
    u16* Bcat_b = (u16*)(base + off); off += 524288;
    u16* WnI_b  = (u16*)(base + off); off += 131072;
    u16* WnH_b  = (u16*)(base + off); off += 131072;
    float* brz  = (float*)(base + off); off += 2048;
    float* be4  = (float*)(base + off); off += 4096;

    if (ws_size < off) {
        wsfail_kernel<<<(out_size + 255) / 256, 256, 0, stream>>>(
            outf, (float)(ws_size >> 20), out_size);
        return;
    }

    // ---- once per launch: weight pack + CSR build + pad-row zeroing ----
    hipMemsetAsync(rowptr, 0, (size_t)4 * (N_NODES + 1) * 4, stream);
    hipMemsetAsync(Hmean2 + (size_t)N_NODES * 512, 0, (size_t)(M_PAD - N_NODES) * 512 * 2, stream);
    hipMemsetAsync(aggb + (size_t)N_NODES * 256, 0, (size_t)(M_PAD - N_NODES) * 256 * 2, stream);
    hipMemsetAsync(h_bf + (size_t)N_NODES * 256, 0, (size_t)(M_PAD - N_NODES) * 256 * 2, stream);
    prep_kernel<<<1024, 256, 0, stream>>>(
        We[0], We[1], We[2], We[3], be[0], be[1], be[2], be[3],
        W_ih, W_hh, b_ih, b_hh, Wrz_b, Bcat_b, WnI_b, WnH_b, brz, be4);
    xcvt_kernel<<<N_NODES * D / 4 / 256, 256, 0, stream>>>(x, h_bf);
    cnt_kernel<<<(4 * E_EDGES + 255) / 256, 256, 0, stream>>>(
        de[0], de[1], de[2], de[3], rowptr);
    scan1_kernel<<<dim3(SCHUNKS, 4), 256, 0, stream>>>(rowptr, bsum);
    scan2_kernel<<<4, 256, 0, stream>>>(bsum);
    scan3_kernel<<<dim3(SCHUNKS, 4), 256, 0, stream>>>(rowptr, bsum);
    fill_csr_kernel<<<(4 * E_EDGES + 255) / 256, 256, 0, stream>>>(
        se[0], de[0], se[1], de[1], se[2], de[2], se[3], de[3], rowptr, colb);
    degmask_kernel<<<(N_NODES + 255) / 256, 256, 0, stream>>>(rowptr, degmask);

    const dim3 g2(2, 391), g4(4, 391);
    for (int step = 0; step < 3; ++step) {
        // agg (pair 0): Hmean2{e0,e1} @ Bcat0^T + masked biases -> aggb
        gather2_kernel<<<N_NODES / 2, 256, 0, stream>>>(h_bf, rowptr, colb, Hmean2, 0);
        gemm_mfma<3, false><<<g2, 256, 0, stream>>>(
            Hmean2, 512, nullptr, 0, Bcat_b, aggb, 256,
            256, 512, 8, be4, be4 + 256, degmask, 0);
        // agg (pair 1): accumulate
        gather2_kernel<<<N_NODES / 2, 256, 0, stream>>>(h_bf, rowptr, colb, Hmean2, 1);
        gemm_mfma<3, true><<<g2, 256, 0, stream>>>(
            Hmean2, 512, nullptr, 0, Bcat_b + 131072, aggb, 256,
            256, 512, 8, be4 + 512, be4 + 768, degmask, 2);

        // rz = [agg | h] @ Wrz^T + brz   (K=512: kt<4 aggb, kt>=4 h_bf)
        gemm_mfma<1, false><<<g4, 256, 0, stream>>>(
            aggb, 256, h_bf, 256, Wrz_b, rzb, 512,
            512, 512, 4, brz, nullptr, nullptr, 0);
        // i_n = agg @ WnI^T + b_in
        gemm_mfma<1, false><<<g2, 256, 0, stream>>>(
            aggb, 256, nullptr, 0, WnI_b, ninb, 256,
            256, 256, 4, b_ih + 512, nullptr, nullptr, 0);
        // h_n = h @ WnH^T + b_hn   (writes hnb = aggb alias; aggb dead now)
        gemm_mfma<1, false><<<g2, 256, 0, stream>>>(
            h_bf, 256, nullptr, 0, WnH_b, hnb, 256,
            256, 256, 4, b_hh + 512, nullptr, nullptr, 0);

        // steps 0,1 -> h_bf (bf16, in-place safe); step 2 -> d_out (f32)
        if (step < 2)
            gru_ln_kernel<0><<<N_NODES / 4, 256, 0, stream>>>(
                rzb, ninb, hnb, h_bf, h_bf, gamma, beta);
        else
            gru_ln_kernel<1><<<N_NODES / 4, 256, 0, stream>>>(
                rzb, ninb, hnb, h_bf, outf, gamma, beta);
    }
}

// Round 10
// 946.378 us; speedup vs baseline: 15.9413x; 1.1943x over previous
//
#include <hip/hip_runtime.h>
#include <hip/hip_bf16.h>
#include <cstddef>

#define N_NODES 50000
#define E_EDGES 300000
#define D 256
#define M_PAD 50048           // 391 * 128
#define SCHUNKS 196           // ceil(50001/256)

typedef unsigned short u16;
typedef __attribute__((ext_vector_type(8))) short bf16x8;   // 8 bf16 = 4 VGPRs
typedef __attribute__((ext_vector_type(4))) float f32x4;

__device__ __forceinline__ float b2f(u16 u) {
    return __uint_as_float(((unsigned)u) << 16);
}
__device__ __forceinline__ u16 f2b(float f) {
    __hip_bfloat16 h = __float2bfloat16(f);
    return *reinterpret_cast<u16*>(&h);
}
__device__ __forceinline__ void async16(const u16* g, u16* l) {
    __builtin_amdgcn_global_load_lds(
        (const __attribute__((address_space(1))) void*)g,
        (__attribute__((address_space(3))) void*)l, 16, 0, 0);
}

// ---------------------------------------------------------------------------
// prep: pack all weights to bf16 once.
//   Bfull[j][k] (768x512) = k<256 ? W_ih[j][k] : (j<512 ? W_hh[j][k-256] : 0)
//     rows 0-511 = Wrz (r,z gates, dual [agg|h]); rows 512-767 = WnI (agg only)
//   bfull[j] (768, f32) = b_ih[j] + (j<512 ? b_hh[j] : 0)
//   Bcat_b[p][j][el*256+kk] = W_{2p+el}[j][kk]   (2 x 256 x 512)
//   WnH_b[j][k] = W_hh[512+j][k]                 (256x256)
//   be4[e][k] = b_e[k] (f32)
// grid: 1536 x 256 = 393216 threads
// ---------------------------------------------------------------------------
__global__ __launch_bounds__(256) void prep_kernel(
    const float* __restrict__ W0, const float* __restrict__ W1,
    const float* __restrict__ W2, const float* __restrict__ W3,
    const float* __restrict__ b0, const float* __restrict__ b1,
    const float* __restrict__ b2, const float* __restrict__ b3,
    const float* __restrict__ W_ih, const float* __restrict__ W_hh,
    const float* __restrict__ b_ih, const float* __restrict__ b_hh,
    u16* __restrict__ Bfull_b, u16* __restrict__ Bcat_b,
    u16* __restrict__ WnH_b,
    float* __restrict__ bfull, float* __restrict__ be4)
{
    int t = blockIdx.x * 256 + threadIdx.x;    // [0, 393216)
    if (t < 393216) {
        int j = t >> 9, k = t & 511;
        float v;
        if (k < 256)      v = W_ih[j * 256 + k];
        else if (j < 512) v = W_hh[j * 256 + (k - 256)];
        else              v = 0.f;
        Bfull_b[t] = f2b(v);
    }
    if (t < 262144) {
        int p = t >> 17, rem = t & 131071;
        int j = rem >> 9, k = rem & 511;
        int e = p * 2 + (k >> 8), kk = k & 255;
        const float* W = (e == 0) ? W0 : (e == 1) ? W1 : (e == 2) ? W2 : W3;
        Bcat_b[t] = f2b(W[j * 256 + kk]);
    }
    if (t < 65536) WnH_b[t] = f2b(W_hh[131072 + t]);
    if (t < 768)   bfull[t] = b_ih[t] + (t < 512 ? b_hh[t] : 0.f);
    if (t < 1024) {
        int e = t >> 8, k = t & 255;
        const float* b = (e == 0) ? b0 : (e == 1) ? b1 : (e == 2) ? b2 : b3;
        be4[t] = b[k];
    }
}

__global__ __launch_bounds__(256) void xcvt_kernel(
    const float* __restrict__ x, u16* __restrict__ hb)
{
    int t = blockIdx.x * 256 + threadIdx.x;      // 4-elem slot
    float4 v = *reinterpret_cast<const float4*>(x + (size_t)t * 4);
    ushort4 o;
    o.x = f2b(v.x); o.y = f2b(v.y); o.z = f2b(v.z); o.w = f2b(v.w);
    *reinterpret_cast<ushort4*>(hb + (size_t)t * 4) = o;
}

// ---------------------------------------------------------------------------
// CSR build. counts at rp[e][dst+1]; after scan rp[n] = beg(n); fill uses
// rp as cursor so post-fill rp[n] = end(n); beg(n) = n ? rp[n-1] : 0.
// ---------------------------------------------------------------------------
__global__ __launch_bounds__(256) void cnt_kernel(
    const int* __restrict__ d0, const int* __restrict__ d1,
    const int* __restrict__ d2, const int* __restrict__ d3,
    int* __restrict__ rowptr)
{
    int i = blockIdx.x * 256 + threadIdx.x;
    if (i >= 4 * E_EDGES) return;
    int e = i / E_EDGES;
    int k = i - e * E_EDGES;
    const int* dp = (e == 0) ? d0 : (e == 1) ? d1 : (e == 2) ? d2 : d3;
    atomicAdd(&rowptr[e * (N_NODES + 1) + dp[k] + 1], 1);
}

__global__ __launch_bounds__(256) void scan1_kernel(
    int* __restrict__ rowptr, int* __restrict__ bsum)
{
    int e = blockIdx.y;
    int blk = blockIdx.x;
    int t = threadIdx.x;
    int idx = blk * 256 + t;
    int* rp = rowptr + e * (N_NODES + 1);
    int v = (idx <= N_NODES) ? rp[idx] : 0;
    __shared__ int s[256];
    s[t] = v;
    __syncthreads();
    for (int o = 1; o < 256; o <<= 1) {
        int u = (t >= o) ? s[t - o] : 0;
        __syncthreads();
        s[t] += u;
        __syncthreads();
    }
    if (idx <= N_NODES) rp[idx] = s[t];
    if (t == 255) bsum[e * SCHUNKS + blk] = s[255];
}

__global__ __launch_bounds__(256) void scan2_kernel(int* __restrict__ bsum)
{
    int e = blockIdx.x;
    int t = threadIdx.x;
    int v = (t < SCHUNKS) ? bsum[e * SCHUNKS + t] : 0;
    __shared__ int s[256];
    s[t] = v;
    __syncthreads();
    for (int o = 1; o < 256; o <<= 1) {
        int u = (t >= o) ? s[t - o] : 0;
        __syncthreads();
        s[t] += u;
        __syncthreads();
    }
    if (t < SCHUNKS) bsum[e * SCHUNKS + t] = s[t];
}

__global__ __launch_bounds__(256) void scan3_kernel(
    int* __restrict__ rowptr, const int* __restrict__ bsum)
{
    int e = blockIdx.y;
    int blk = blockIdx.x;
    if (blk == 0) return;
    int idx = blk * 256 + threadIdx.x;
    if (idx > N_NODES) return;
    rowptr[e * (N_NODES + 1) + idx] += bsum[e * SCHUNKS + blk - 1];
}

__global__ __launch_bounds__(256) void fill_csr_kernel(
    const int* __restrict__ s0, const int* __restrict__ d0,
    const int* __restrict__ s1, const int* __restrict__ d1,
    const int* __restrict__ s2, const int* __restrict__ d2,
    const int* __restrict__ s3, const int* __restrict__ d3,
    int* __restrict__ rowptr, u16* __restrict__ colb)
{
    int i = blockIdx.x * 256 + threadIdx.x;
    if (i >= 4 * E_EDGES) return;
    int e = i / E_EDGES;
    int k = i - e * E_EDGES;
    const int* sp = (e == 0) ? s0 : (e == 1) ? s1 : (e == 2) ? s2 : s3;
    const int* dp = (e == 0) ? d0 : (e == 1) ? d1 : (e == 2) ? d2 : d3;
    int dst = dp[k];
    int slot = atomicAdd(&rowptr[e * (N_NODES + 1) + dst], 1);
    colb[(size_t)e * E_EDGES + slot] = (u16)sp[k];
}

__global__ __launch_bounds__(256) void degmask_kernel(
    const int* __restrict__ rowptr, unsigned char* __restrict__ degmask)
{
    int n = blockIdx.x * 256 + threadIdx.x;
    if (n >= N_NODES) return;
    int m = 0;
#pragma unroll
    for (int e = 0; e < 4; ++e) {
        const int* rp = rowptr + e * (N_NODES + 1);
        int beg = n ? rp[n - 1] : 0;
        if (rp[n] > beg) m |= (1 << e);
    }
    degmask[n] = (unsigned char)m;
}

// ---------------------------------------------------------------------------
// gather2: Hmean2[n][el*256+c] = mean over in-edges(2*pair+el) of hb[src][c]
// 4-deep ILP: 4 independent accumulators, 4 row-loads in flight per wave.
// ---------------------------------------------------------------------------
__global__ __launch_bounds__(256) void gather2_kernel(
    const u16* __restrict__ hb, const int* __restrict__ rowptr,
    const u16* __restrict__ colb, u16* __restrict__ Hmean2, int pair)
{
    int n = blockIdx.x * 2 + (threadIdx.x >> 7);
    int el = (threadIdx.x >> 6) & 1;
    int lane = threadIdx.x & 63;
    int e = pair * 2 + el;
    const int* rp = rowptr + e * (N_NODES + 1);
    int beg = n ? rp[n - 1] : 0;
    int end = rp[n];
    const u16* cb = colb + (size_t)e * E_EDGES;

    float4 a0 = make_float4(0.f, 0.f, 0.f, 0.f);
    float4 a1 = a0, a2 = a0, a3 = a0;
    int j = beg;
    for (; j + 4 <= end; j += 4) {
        int s0 = cb[j], s1 = cb[j + 1], s2 = cb[j + 2], s3 = cb[j + 3];
        ushort4 u0 = *reinterpret_cast<const ushort4*>(hb + (size_t)s0 * D + lane * 4);
        ushort4 u1 = *reinterpret_cast<const ushort4*>(hb + (size_t)s1 * D + lane * 4);
        ushort4 u2 = *reinterpret_cast<const ushort4*>(hb + (size_t)s2 * D + lane * 4);
        ushort4 u3 = *reinterpret_cast<const ushort4*>(hb + (size_t)s3 * D + lane * 4);
        a0.x += b2f(u0.x); a0.y += b2f(u0.y); a0.z += b2f(u0.z); a0.w += b2f(u0.w);
        a1.x += b2f(u1.x); a1.y += b2f(u1.y); a1.z += b2f(u1.z); a1.w += b2f(u1.w);
        a2.x += b2f(u2.x); a2.y += b2f(u2.y); a2.z += b2f(u2.z); a2.w += b2f(u2.w);
        a3.x += b2f(u3.x); a3.y += b2f(u3.y); a3.z += b2f(u3.z); a3.w += b2f(u3.w);
    }
    for (; j < end; ++j) {
        int s0 = cb[j];
        ushort4 u0 = *reinterpret_cast<const ushort4*>(hb + (size_t)s0 * D + lane * 4);
        a0.x += b2f(u0.x); a0.y += b2f(u0.y); a0.z += b2f(u0.z); a0.w += b2f(u0.w);
    }
    float ax = (a0.x + a1.x) + (a2.x + a3.x);
    float ay = (a0.y + a1.y) + (a2.y + a3.y);
    float az = (a0.z + a1.z) + (a2.z + a3.z);
    float aw = (a0.w + a1.w) + (a2.w + a3.w);
    float s = (end > beg) ? 1.f / (float)(end - beg) : 0.f;
    ushort4 o;
    o.x = f2b(ax * s); o.y = f2b(ay * s); o.z = f2b(az * s); o.w = f2b(aw * s);
    *reinterpret_cast<ushort4*>(Hmean2 + (size_t)n * 512 + el * 256 + lane * 4) = o;
}

// ---------------------------------------------------------------------------
// MFMA GEMM, 128x128 tile, BK=64, XOR-swizzled LDS, global_load_lds staging,
// bijective XCD block swizzle.
// Split-output: col-blocks with bn < split write C0 (ldc0) over K (nkt=K/64);
// bn >= split write C1 (ldc1, col-split) over K = KS*64 only (A0 range).
// A: kt < KS from A0 (lda0), else A1 (lda1).
// BIASK 1: bias0[global col]. BIASK 3: per-row etype-pair masked bias0/bias1.
// ---------------------------------------------------------------------------
template <int BIASK, bool ACCUM>
__global__ __launch_bounds__(256) void gemm_mfma(
    const u16* __restrict__ A0, int lda0,
    const u16* __restrict__ A1, int lda1,
    const u16* __restrict__ Bw,
    u16* __restrict__ C0, int ldc0, u16* __restrict__ C1, int ldc1, int split,
    int K, int KS,
    const float* __restrict__ bias0, const float* __restrict__ bias1,
    const unsigned char* __restrict__ degmask, int mshift)
{
    __shared__ u16 As[8192];    // 128 x 64 bf16 (16 KB)
    __shared__ u16 Bs2[8192];

    const int gx = gridDim.x;
    const int nwg = gx * gridDim.y;
    const int lin = blockIdx.y * gx + blockIdx.x;
    const int q = nwg >> 3, r = nwg & 7;
    const int xcd = lin & 7, pos = lin >> 3;
    const int wg = (xcd < r) ? xcd * (q + 1) + pos
                             : r * (q + 1) + (xcd - r) * q + pos;
    const int by = wg / gx;
    const int bx = wg - by * gx;
    const int bm = by * 128;
    const int bn = bx * 128;

    const int tid = threadIdx.x;
    const int lane = tid & 63;
    const int wid = tid >> 6;
    const int wr = wid >> 1;
    const int wc = wid & 1;
    const int l15 = lane & 15;
    const int l4 = lane >> 4;

    int srow[4], schk[4];
#pragma unroll
    for (int i = 0; i < 4; ++i) {
        int qq = (wid * 4 + i) * 64 + lane;
        srow[i] = qq >> 3;
        schk[i] = (qq & 7) ^ (srow[i] & 7);
    }

    f32x4 acc[4][4];
#pragma unroll
    for (int i = 0; i < 4; ++i)
#pragma unroll
        for (int j = 0; j < 4; ++j)
            acc[i][j] = (f32x4){0.f, 0.f, 0.f, 0.f};

    const int nkt = (bn < split) ? (K >> 6) : KS;
    for (int kt = 0; kt < nkt; ++kt) {
        const u16* Ab = (kt < KS) ? A0 + (size_t)kt * 64
                                  : A1 + (size_t)(kt - KS) * 64;
        const int lda = (kt < KS) ? lda0 : lda1;
#pragma unroll
        for (int i = 0; i < 4; ++i)
            async16(Ab + (size_t)(bm + srow[i]) * lda + schk[i] * 8,
                    &As[(wid * 4 + i) * 512]);
#pragma unroll
        for (int i = 0; i < 4; ++i)
            async16(Bw + (size_t)(bn + srow[i]) * K + kt * 64 + schk[i] * 8,
                    &Bs2[(wid * 4 + i) * 512]);
        __syncthreads();

#pragma unroll
        for (int kk = 0; kk < 2; ++kk) {
            bf16x8 a[4], b[4];
#pragma unroll
            for (int i = 0; i < 4; ++i) {
                int ar = wr * 64 + i * 16 + l15;
                a[i] = *reinterpret_cast<const bf16x8*>(
                    &As[ar * 64 + (((kk * 4 + l4) ^ (ar & 7)) << 3)]);
                int bc = wc * 64 + i * 16 + l15;
                b[i] = *reinterpret_cast<const bf16x8*>(
                    &Bs2[bc * 64 + (((kk * 4 + l4) ^ (bc & 7)) << 3)]);
            }
#pragma unroll
            for (int i = 0; i < 4; ++i)
#pragma unroll
                for (int j = 0; j < 4; ++j)
                    acc[i][j] = __builtin_amdgcn_mfma_f32_16x16x32_bf16(
                        a[i], b[j], acc[i][j], 0, 0, 0);
        }
        __syncthreads();
    }

    // output routing (block-uniform)
    u16* Cw; int ldc, cb0;
    if (bn < split) { Cw = C0; ldc = ldc0; cb0 = bn; }
    else            { Cw = C1; ldc = ldc1; cb0 = bn - split; }

    // epilogue: C/D frag layout col = lane&15, row = (lane>>4)*4 + reg
    float bj0[4], bj1[4];
#pragma unroll
    for (int j = 0; j < 4; ++j) {
        int col = bn + wc * 64 + j * 16 + l15;
        bj0[j] = bias0[col];
        if (BIASK == 3) bj1[j] = bias1[col];
    }
#pragma unroll
    for (int i = 0; i < 4; ++i) {
        int row0 = bm + wr * 64 + i * 16 + l4 * 4;
#pragma unroll
        for (int r2 = 0; r2 < 4; ++r2) {
            int row = row0 + r2;
            if (row < N_NODES) {
                float m0 = 1.f, m1 = 0.f;
                if (BIASK == 3) {
                    int bits = degmask[row] >> mshift;
                    m0 = (bits & 1) ? 1.f : 0.f;
                    m1 = (bits & 2) ? 1.f : 0.f;
                }
#pragma unroll
                for (int j = 0; j < 4; ++j) {
                    int col = cb0 + wc * 64 + j * 16 + l15;
                    float o = acc[i][j][r2];
                    if (BIASK == 3) o += m0 * bj0[j] + m1 * bj1[j];
                    else            o += bj0[j];
                    u16* cp = Cw + (size_t)row * ldc + col;
                    if (ACCUM) o += b2f(*cp);
                    *cp = f2b(o);
                }
            }
        }
    }
}

// ---------------------------------------------------------------------------
// fused GRU cell + LayerNorm: one WAVE per node, vectorized, shuffle-only.
// ---------------------------------------------------------------------------
template <int OUTM>
__global__ __launch_bounds__(256) void gru_ln_kernel(
    const u16* __restrict__ rz, const u16* __restrict__ nin,
    const u16* __restrict__ hn, const u16* __restrict__ hb,
    void* __restrict__ outv,
    const float* __restrict__ gamma, const float* __restrict__ beta)
{
    int w = threadIdx.x >> 6;
    int l = threadIdx.x & 63;
    int n = blockIdx.x * 4 + w;
    size_t b2 = (size_t)n * 512;
    size_t b1 = (size_t)n * D;

    u16 ra[4], za[4], na[4], ha[4], va[4];
    *reinterpret_cast<ushort4*>(ra) = *reinterpret_cast<const ushort4*>(rz + b2 + l * 4);
    *reinterpret_cast<ushort4*>(za) = *reinterpret_cast<const ushort4*>(rz + b2 + 256 + l * 4);
    *reinterpret_cast<ushort4*>(na) = *reinterpret_cast<const ushort4*>(nin + b1 + l * 4);
    *reinterpret_cast<ushort4*>(ha) = *reinterpret_cast<const ushort4*>(hn + b1 + l * 4);
    *reinterpret_cast<ushort4*>(va) = *reinterpret_cast<const ushort4*>(hb + b1 + l * 4);

    float hnew[4];
    float s1 = 0.f, s2 = 0.f;
#pragma unroll
    for (int c = 0; c < 4; ++c) {
        float r = 1.f / (1.f + __expf(-b2f(ra[c])));
        float z = 1.f / (1.f + __expf(-b2f(za[c])));
        float xn = b2f(na[c]) + r * b2f(ha[c]);
        float nn = 2.f / (1.f + __expf(-2.f * xn)) - 1.f;   // tanh
        hnew[c] = (1.f - z) * nn + z * b2f(va[c]);
        s1 += hnew[c];
        s2 += hnew[c] * hnew[c];
    }
#pragma unroll
    for (int o = 32; o > 0; o >>= 1) {
        s1 += __shfl_down(s1, o);
        s2 += __shfl_down(s2, o);
    }
    float sum = __shfl(s1, 0);
    float ssq = __shfl(s2, 0);
    float mu = sum * (1.f / D);
    float var = ssq * (1.f / D) - mu * mu;
    float rstd = rsqrtf(var + 1e-5f);

    float4 g = *reinterpret_cast<const float4*>(gamma + l * 4);
    float4 bt = *reinterpret_cast<const float4*>(beta + l * 4);
    float res[4];
    res[0] = (hnew[0] - mu) * rstd * g.x + bt.x;
    res[1] = (hnew[1] - mu) * rstd * g.y + bt.y;
    res[2] = (hnew[2] - mu) * rstd * g.z + bt.z;
    res[3] = (hnew[3] - mu) * rstd * g.w + bt.w;

    if (OUTM == 0) {
        ushort4 o;
        o.x = f2b(res[0]); o.y = f2b(res[1]); o.z = f2b(res[2]); o.w = f2b(res[3]);
        *reinterpret_cast<ushort4*>((u16*)outv + b1 + l * 4) = o;
    } else {
        *reinterpret_cast<float4*>((float*)outv + b1 + l * 4) =
            make_float4(res[0], res[1], res[2], res[3]);
    }
}

__global__ __launch_bounds__(256) void wsfail_kernel(float* __restrict__ out, float val, int n)
{
    int i = blockIdx.x * 256 + threadIdx.x;
    if (i < n) out[i] = val;
}

// ---------------------------------------------------------------------------
extern "C" void kernel_launch(void* const* d_in, const int* in_sizes, int n_in,
                              void* d_out, int out_size, void* d_ws, size_t ws_size,
                              hipStream_t stream)
{
    const float* x    = (const float*)d_in[0];
    const int* se[4] = {(const int*)d_in[1], (const int*)d_in[5],
                        (const int*)d_in[9], (const int*)d_in[13]};
    const int* de[4] = {(const int*)d_in[2], (const int*)d_in[6],
                        (const int*)d_in[10], (const int*)d_in[14]};
    const float* We[4] = {(const float*)d_in[3], (const float*)d_in[7],
                          (const float*)d_in[11], (const float*)d_in[15]};
    const float* be[4] = {(const float*)d_in[4], (const float*)d_in[8],
                          (const float*)d_in[12], (const float*)d_in[16]};
    const float* W_ih = (const float*)d_in[17];
    const float* W_hh = (const float*)d_in[18];
    const float* b_ih = (const float*)d_in[19];
    const float* b_hh = (const float*)d_in[20];
    const float* gamma = (const float*)d_in[21];
    const float* beta  = (const float*)d_in[22];
    float* outf = (float*)d_out;          // f32 [N,D], written at final step only

    // ---- workspace layout (bytes), total ~133 MB ----
    char* base = (char*)d_ws;
    size_t off = 0;
    u16* Hmean2 = (u16*)(base + off); off += (size_t)M_PAD * 512 * 2;  // 51.25 MB
    u16* rzb    = Hmean2;             // alias: Hmean2 dead before rz GEMM writes
    u16* aggb = (u16*)(base + off); off += (size_t)M_PAD * 256 * 2;    // 25.62 MB
    u16* hnb  = aggb;                 // alias: aggb dead before hn GEMM writes
    u16* ninb = (u16*)(base + off); off += (size_t)N_NODES * 256 * 2;  // 25.6 MB
    u16* h_bf = (u16*)(base + off); off += (size_t)M_PAD * 256 * 2;    // 25.62 MB
    int* rowptr = (int*)(base + off); off += (size_t)4 * (N_NODES + 1) * 4;
    u16* colb = (u16*)(base + off); off += (size_t)4 * E_EDGES * 2;
    unsigned char* degmask = (unsigned char*)(base + off); off += 50048;
    int* bsum = (int*)(base + off); off += (size_t)4 * SCHUNKS * 4;
    u16* Bfull_b = (u16*)(base + off); off += 786432;   // 768x512 bf16
    u16* Bcat_b  = (u16*)(base + off); off += 524288;   // 2x256x512 bf16
    u16* WnH_b   = (u16*)(base + off); off += 131072;   // 256x256 bf16
    float* bfull = (float*)(base + off); off += 3072;   // 768 f32
    float* be4   = (float*)(base + off); off += 4096;   // 1024 f32

    if (ws_size < off) {
        wsfail_kernel<<<(out_size + 255) / 256, 256, 0, stream>>>(
            outf, (float)(ws_size >> 20), out_size);
        return;
    }

    // ---- once per launch: weight pack + CSR build + pad-row zeroing ----
    hipMemsetAsync(rowptr, 0, (size_t)4 * (N_NODES + 1) * 4, stream);
    hipMemsetAsync(Hmean2 + (size_t)N_NODES * 512, 0, (size_t)(M_PAD - N_NODES) * 512 * 2, stream);
    hipMemsetAsync(aggb + (size_t)N_NODES * 256, 0, (size_t)(M_PAD - N_NODES) * 256 * 2, stream);
    hipMemsetAsync(h_bf + (size_t)N_NODES * 256, 0, (size_t)(M_PAD - N_NODES) * 256 * 2, stream);
    prep_kernel<<<1536, 256, 0, stream>>>(
        We[0], We[1], We[2], We[3], be[0], be[1], be[2], be[3],
        W_ih, W_hh, b_ih, b_hh, Bfull_b, Bcat_b, WnH_b, bfull, be4);
    xcvt_kernel<<<N_NODES * D / 4 / 256, 256, 0, stream>>>(x, h_bf);
    cnt_kernel<<<(4 * E_EDGES + 255) / 256, 256, 0, stream>>>(
        de[0], de[1], de[2], de[3], rowptr);
    scan1_kernel<<<dim3(SCHUNKS, 4), 256, 0, stream>>>(rowptr, bsum);
    scan2_kernel<<<4, 256, 0, stream>>>(bsum);
    scan3_kernel<<<dim3(SCHUNKS, 4), 256, 0, stream>>>(rowptr, bsum);
    fill_csr_kernel<<<(4 * E_EDGES + 255) / 256, 256, 0, stream>>>(
        se[0], de[0], se[1], de[1], se[2], de[2], se[3], de[3], rowptr, colb);
    degmask_kernel<<<(N_NODES + 255) / 256, 256, 0, stream>>>(rowptr, degmask);

    const dim3 g2(2, 391), g6(6, 391);
    for (int step = 0; step < 3; ++step) {
        // agg (pair 0): Hmean2{e0,e1} @ Bcat0^T + masked biases -> aggb
        gather2_kernel<<<N_NODES / 2, 256, 0, stream>>>(h_bf, rowptr, colb, Hmean2, 0);
        gemm_mfma<3, false><<<g2, 256, 0, stream>>>(
            Hmean2, 512, nullptr, 0, Bcat_b, aggb, 256, aggb, 256, 256,
            512, 8, be4, be4 + 256, degmask, 0);
        // agg (pair 1): accumulate
        gather2_kernel<<<N_NODES / 2, 256, 0, stream>>>(h_bf, rowptr, colb, Hmean2, 1);
        gemm_mfma<3, true><<<g2, 256, 0, stream>>>(
            Hmean2, 512, nullptr, 0, Bcat_b + 131072, aggb, 256, aggb, 256, 256,
            512, 8, be4 + 512, be4 + 768, degmask, 2);

        // fused rz+nin: cols<512 = [agg|h]@Wrz^T (K=512); cols>=512 = agg@WnI^T (K=256)
        gemm_mfma<1, false><<<g6, 256, 0, stream>>>(
            aggb, 256, h_bf, 256, Bfull_b, rzb, 512, ninb, 256, 512,
            512, 4, bfull, nullptr, nullptr, 0);
        // h_n = h @ WnH^T + b_hn   (writes hnb = aggb alias; aggb dead now)
        gemm_mfma<1, false><<<g2, 256, 0, stream>>>(
            h_bf, 256, nullptr, 0, WnH_b, hnb, 256, hnb, 256, 256,
            256, 4, b_hh + 512, nullptr, nullptr, 0);

        // steps 0,1 -> h_bf (bf16, in-place safe); step 2 -> d_out (f32)
        if (step < 2)
            gru_ln_kernel<0><<<N_NODES / 4, 256, 0, stream>>>(
                rzb, ninb, hnb, h_bf, h_bf, gamma, beta);
        else
            gru_ln_kernel<1><<<N_NODES / 4, 256, 0, stream>>>(
                rzb, ninb, hnb, h_bf, outf, gamma, beta);
    }
}

// Round 11
// 813.081 us; speedup vs baseline: 18.5547x; 1.1639x over previous
//
#include <hip/hip_runtime.h>
#include <hip/hip_bf16.h>
#include <cstddef>

#define N_NODES 50000
#define E_EDGES 300000
#define D 256
#define SCHUNKS 196           // ceil(50001/256)

typedef unsigned short u16;
typedef __attribute__((ext_vector_type(8))) short bf16x8;   // 8 bf16 = 4 VGPRs
typedef __attribute__((ext_vector_type(4))) float f32x4;

__device__ __forceinline__ float b2f(u16 u) {
    return __uint_as_float(((unsigned)u) << 16);
}
__device__ __forceinline__ u16 f2b(float f) {
    __hip_bfloat16 h = __float2bfloat16(f);
    return *reinterpret_cast<u16*>(&h);
}
__device__ __forceinline__ void async16(const u16* g, u16* l) {
    __builtin_amdgcn_global_load_lds(
        (const __attribute__((address_space(1))) void*)g,
        (__attribute__((address_space(3))) void*)l, 16, 0, 0);
}

// ---------------------------------------------------------------------------
// prep: pack weights to bf16 once.
//  Bfull[j][k] (1024x512):
//    k<256 : j<768 ? W_ih[j][k] : W_hh[j-256][k]     (rz + i_n + h_n rows)
//    k>=256: j<512 ? W_hh[j][k-256] : 0
//  Bcat1024[j][k] (256x1024) = W_{k>>8}[j][k&255]
//  bfull[1024] = j<512: b_ih+b_hh; 512-767: b_ih[j]; 768-1023: b_hh[j-256]
//  be4[e*256+k] = b_e[k]
// ---------------------------------------------------------------------------
__global__ __launch_bounds__(256) void prep_kernel(
    const float* __restrict__ W0, const float* __restrict__ W1,
    const float* __restrict__ W2, const float* __restrict__ W3,
    const float* __restrict__ b0, const float* __restrict__ b1,
    const float* __restrict__ b2, const float* __restrict__ b3,
    const float* __restrict__ W_ih, const float* __restrict__ W_hh,
    const float* __restrict__ b_ih, const float* __restrict__ b_hh,
    u16* __restrict__ Bfull_b, u16* __restrict__ Bcat_b,
    float* __restrict__ bfull, float* __restrict__ be4)
{
    int t = blockIdx.x * 256 + threadIdx.x;    // [0, 524288)
    {
        int j = t >> 9, k = t & 511;
        float v;
        if (k < 256) v = (j < 768) ? W_ih[j * 256 + k] : W_hh[(j - 256) * 256 + k];
        else         v = (j < 512) ? W_hh[j * 256 + (k - 256)] : 0.f;
        Bfull_b[t] = f2b(v);
    }
    if (t < 262144) {
        int j = t >> 10, k = t & 1023;
        int e = k >> 8, kk = k & 255;
        const float* W = (e == 0) ? W0 : (e == 1) ? W1 : (e == 2) ? W2 : W3;
        Bcat_b[t] = f2b(W[j * 256 + kk]);
    }
    if (t < 1024) {
        bfull[t] = (t < 512) ? b_ih[t] + b_hh[t]
                 : (t < 768) ? b_ih[t] : b_hh[t - 256];
        int e = t >> 8, k = t & 255;
        const float* b = (e == 0) ? b0 : (e == 1) ? b1 : (e == 2) ? b2 : b3;
        be4[t] = b[k];
    }
}

__global__ __launch_bounds__(256) void xcvt_kernel(
    const float* __restrict__ x, u16* __restrict__ hb)
{
    int t = blockIdx.x * 256 + threadIdx.x;      // 4-elem slot
    float4 v = *reinterpret_cast<const float4*>(x + (size_t)t * 4);
    ushort4 o;
    o.x = f2b(v.x); o.y = f2b(v.y); o.z = f2b(v.z); o.w = f2b(v.w);
    *reinterpret_cast<ushort4*>(hb + (size_t)t * 4) = o;
}

// ---------------------------------------------------------------------------
// CSR build, rank-based (one atomic pass):
//  cnt: counts at rp[e][dst+1], stores per-edge rank (old count).
//  scan: rp = inclusive scan -> beg(n)=rp[n], end(n)=rp[n+1].
//  fill: slot = rp[dst] + rank (no atomics; rowptr not modified).
// ---------------------------------------------------------------------------
__global__ __launch_bounds__(256) void cnt_kernel(
    const int* __restrict__ d0, const int* __restrict__ d1,
    const int* __restrict__ d2, const int* __restrict__ d3,
    int* __restrict__ rowptr, u16* __restrict__ rank)
{
    int i = blockIdx.x * 256 + threadIdx.x;
    if (i >= 4 * E_EDGES) return;
    int e = i / E_EDGES;
    int k = i - e * E_EDGES;
    const int* dp = (e == 0) ? d0 : (e == 1) ? d1 : (e == 2) ? d2 : d3;
    rank[i] = (u16)atomicAdd(&rowptr[e * (N_NODES + 1) + dp[k] + 1], 1);
}

__global__ __launch_bounds__(256) void scan1_kernel(
    int* __restrict__ rowptr, int* __restrict__ bsum)
{
    int e = blockIdx.y;
    int blk = blockIdx.x;
    int t = threadIdx.x;
    int idx = blk * 256 + t;
    int* rp = rowptr + e * (N_NODES + 1);
    int v = (idx <= N_NODES) ? rp[idx] : 0;
    __shared__ int s[256];
    s[t] = v;
    __syncthreads();
    for (int o = 1; o < 256; o <<= 1) {
        int u = (t >= o) ? s[t - o] : 0;
        __syncthreads();
        s[t] += u;
        __syncthreads();
    }
    if (idx <= N_NODES) rp[idx] = s[t];
    if (t == 255) bsum[e * SCHUNKS + blk] = s[255];
}

__global__ __launch_bounds__(256) void scan2_kernel(int* __restrict__ bsum)
{
    int e = blockIdx.x;
    int t = threadIdx.x;
    int v = (t < SCHUNKS) ? bsum[e * SCHUNKS + t] : 0;
    __shared__ int s[256];
    s[t] = v;
    __syncthreads();
    for (int o = 1; o < 256; o <<= 1) {
        int u = (t >= o) ? s[t - o] : 0;
        __syncthreads();
        s[t] += u;
        __syncthreads();
    }
    if (t < SCHUNKS) bsum[e * SCHUNKS + t] = s[t];
}

__global__ __launch_bounds__(256) void scan3_kernel(
    int* __restrict__ rowptr, const int* __restrict__ bsum)
{
    int e = blockIdx.y;
    int blk = blockIdx.x;
    if (blk == 0) return;
    int idx = blk * 256 + threadIdx.x;
    if (idx > N_NODES) return;
    rowptr[e * (N_NODES + 1) + idx] += bsum[e * SCHUNKS + blk - 1];
}

__global__ __launch_bounds__(256) void fill_csr_kernel(
    const int* __restrict__ s0, const int* __restrict__ d0,
    const int* __restrict__ s1, const int* __restrict__ d1,
    const int* __restrict__ s2, const int* __restrict__ d2,
    const int* __restrict__ s3, const int* __restrict__ d3,
    const int* __restrict__ rowptr, const u16* __restrict__ rank,
    u16* __restrict__ colb)
{
    int i = blockIdx.x * 256 + threadIdx.x;
    if (i >= 4 * E_EDGES) return;
    int e = i / E_EDGES;
    int k = i - e * E_EDGES;
    const int* sp = (e == 0) ? s0 : (e == 1) ? s1 : (e == 2) ? s2 : s3;
    const int* dp = (e == 0) ? d0 : (e == 1) ? d1 : (e == 2) ? d2 : d3;
    int dst = dp[k];
    int slot = rowptr[e * (N_NODES + 1) + dst] + (int)rank[i];
    colb[(size_t)e * E_EDGES + slot] = (u16)sp[k];
}

__global__ __launch_bounds__(256) void degmask_kernel(
    const int* __restrict__ rowptr, unsigned char* __restrict__ degmask)
{
    int n = blockIdx.x * 256 + threadIdx.x;
    if (n >= N_NODES) return;
    int m = 0;
#pragma unroll
    for (int e = 0; e < 4; ++e) {
        const int* rp = rowptr + e * (N_NODES + 1);
        if (rp[n + 1] > rp[n]) m |= (1 << e);
    }
    degmask[n] = (unsigned char)m;
}

// ---------------------------------------------------------------------------
// gather: out[n][colblk*256+c] = mean over in-edges(e) of hb[src][c]
// e = pair*2 + el; pairArg<0 -> pair = blockIdx.y (merged all-4-etype launch).
// stride 1024 -> colblk = e (Hmean4); stride 512 -> colblk = el (Hmean2).
// 2 nodes/block, wave=etype-slot, 4-deep ILP.
// ---------------------------------------------------------------------------
__global__ __launch_bounds__(256) void gather_kernel(
    const u16* __restrict__ hb, const int* __restrict__ rowptr,
    const u16* __restrict__ colb, u16* __restrict__ out,
    int pairArg, int stride)
{
    int p = (pairArg < 0) ? (int)blockIdx.y : pairArg;
    int n = blockIdx.x * 2 + (threadIdx.x >> 7);
    int el = (threadIdx.x >> 6) & 1;
    int lane = threadIdx.x & 63;
    int e = p * 2 + el;
    const int* rp = rowptr + e * (N_NODES + 1);
    int beg = rp[n], end = rp[n + 1];
    const u16* cb = colb + (size_t)e * E_EDGES;

    float4 a0 = make_float4(0.f, 0.f, 0.f, 0.f);
    float4 a1 = a0, a2 = a0, a3 = a0;
    int j = beg;
    for (; j + 4 <= end; j += 4) {
        int s0 = cb[j], s1 = cb[j + 1], s2 = cb[j + 2], s3 = cb[j + 3];
        ushort4 u0 = *reinterpret_cast<const ushort4*>(hb + (size_t)s0 * D + lane * 4);
        ushort4 u1 = *reinterpret_cast<const ushort4*>(hb + (size_t)s1 * D + lane * 4);
        ushort4 u2 = *reinterpret_cast<const ushort4*>(hb + (size_t)s2 * D + lane * 4);
        ushort4 u3 = *reinterpret_cast<const ushort4*>(hb + (size_t)s3 * D + lane * 4);
        a0.x += b2f(u0.x); a0.y += b2f(u0.y); a0.z += b2f(u0.z); a0.w += b2f(u0.w);
        a1.x += b2f(u1.x); a1.y += b2f(u1.y); a1.z += b2f(u1.z); a1.w += b2f(u1.w);
        a2.x += b2f(u2.x); a2.y += b2f(u2.y); a2.z += b2f(u2.z); a2.w += b2f(u2.w);
        a3.x += b2f(u3.x); a3.y += b2f(u3.y); a3.z += b2f(u3.z); a3.w += b2f(u3.w);
    }
    for (; j < end; ++j) {
        int s0 = cb[j];
        ushort4 u0 = *reinterpret_cast<const ushort4*>(hb + (size_t)s0 * D + lane * 4);
        a0.x += b2f(u0.x); a0.y += b2f(u0.y); a0.z += b2f(u0.z); a0.w += b2f(u0.w);
    }
    float ax = (a0.x + a1.x) + (a2.x + a3.x);
    float ay = (a0.y + a1.y) + (a2.y + a3.y);
    float az = (a0.z + a1.z) + (a2.z + a3.z);
    float aw = (a0.w + a1.w) + (a2.w + a3.w);
    float s = (end > beg) ? 1.f / (float)(end - beg) : 0.f;
    int colblk = (stride == 1024) ? e : el;
    ushort4 o;
    o.x = f2b(ax * s); o.y = f2b(ay * s); o.z = f2b(az * s); o.w = f2b(aw * s);
    *reinterpret_cast<ushort4*>(out + (size_t)n * stride + colblk * 256 + lane * 4) = o;
}

// ---------------------------------------------------------------------------
// MFMA GEMM, 128x128 tile, BK=64, XOR-swizzled LDS, global_load_lds staging,
// bijective XCD block swizzle. 3 output zones by col-block:
//   bn < split1          : nkt0 k-tiles, kt<KS from A0 else A1   -> C0
//   split1 <= bn < split2: KS  k-tiles, all from A0              -> C1
//   bn >= split2         : KS  k-tiles, all from A1              -> C2
// A rows clamped to N-1 (no padding); C rows guarded.
// BIASK 1: bias0[global col]. 3: 2-mask bias0/bias1 via degmask>>mshift.
// 4: 4-mask from bias0[e*256+col] via degmask bits.
// ---------------------------------------------------------------------------
template <int BIASK, bool ACCUM>
__global__ __launch_bounds__(256) void gemm_mfma(
    const u16* __restrict__ A0, int lda0,
    const u16* __restrict__ A1, int lda1,
    const u16* __restrict__ Bw, int ldb,
    u16* __restrict__ C0, int ldc0, u16* __restrict__ C1, int ldc1,
    u16* __restrict__ C2, int ldc2,
    int split1, int split2, int nkt0, int KS,
    const float* __restrict__ bias0, const float* __restrict__ bias1,
    const unsigned char* __restrict__ degmask, int mshift)
{
    __shared__ u16 As[8192];    // 128 x 64 bf16 (16 KB)
    __shared__ u16 Bs2[8192];

    const int gx = gridDim.x;
    const int nwg = gx * gridDim.y;
    const int lin = blockIdx.y * gx + blockIdx.x;
    const int q = nwg >> 3, r = nwg & 7;
    const int xcd = lin & 7, pos = lin >> 3;
    const int wg = (xcd < r) ? xcd * (q + 1) + pos
                             : r * (q + 1) + (xcd - r) * q + pos;
    const int by = wg / gx;
    const int bx = wg - by * gx;
    const int bm = by * 128;
    const int bn = bx * 128;

    const int tid = threadIdx.x;
    const int lane = tid & 63;
    const int wid = tid >> 6;
    const int wr = wid >> 1;
    const int wc = wid & 1;
    const int l15 = lane & 15;
    const int l4 = lane >> 4;

    int srow[4], schk[4];
#pragma unroll
    for (int i = 0; i < 4; ++i) {
        int qq = (wid * 4 + i) * 64 + lane;
        srow[i] = qq >> 3;
        schk[i] = (qq & 7) ^ (srow[i] & 7);
    }

    f32x4 acc[4][4];
#pragma unroll
    for (int i = 0; i < 4; ++i)
#pragma unroll
        for (int j = 0; j < 4; ++j)
            acc[i][j] = (f32x4){0.f, 0.f, 0.f, 0.f};

    int nkt, ksel;
    if (bn < split1)      { nkt = nkt0; ksel = KS; }
    else if (bn < split2) { nkt = KS;   ksel = KS; }
    else                  { nkt = KS;   ksel = 0;  }

    for (int kt = 0; kt < nkt; ++kt) {
        const u16* Ab; int lda;
        if (kt < ksel) { Ab = A0 + (size_t)kt * 64;          lda = lda0; }
        else           { Ab = A1 + (size_t)(kt - ksel) * 64; lda = lda1; }
#pragma unroll
        for (int i = 0; i < 4; ++i) {
            int rrow = bm + srow[i];
            if (rrow > N_NODES - 1) rrow = N_NODES - 1;
            async16(Ab + (size_t)rrow * lda + schk[i] * 8,
                    &As[(wid * 4 + i) * 512]);
        }
#pragma unroll
        for (int i = 0; i < 4; ++i)
            async16(Bw + (size_t)(bn + srow[i]) * ldb + kt * 64 + schk[i] * 8,
                    &Bs2[(wid * 4 + i) * 512]);
        __syncthreads();

#pragma unroll
        for (int kk = 0; kk < 2; ++kk) {
            bf16x8 a[4], b[4];
#pragma unroll
            for (int i = 0; i < 4; ++i) {
                int ar = wr * 64 + i * 16 + l15;
                a[i] = *reinterpret_cast<const bf16x8*>(
                    &As[ar * 64 + (((kk * 4 + l4) ^ (ar & 7)) << 3)]);
                int bc = wc * 64 + i * 16 + l15;
                b[i] = *reinterpret_cast<const bf16x8*>(
                    &Bs2[bc * 64 + (((kk * 4 + l4) ^ (bc & 7)) << 3)]);
            }
#pragma unroll
            for (int i = 0; i < 4; ++i)
#pragma unroll
                for (int j = 0; j < 4; ++j)
                    acc[i][j] = __builtin_amdgcn_mfma_f32_16x16x32_bf16(
                        a[i], b[j], acc[i][j], 0, 0, 0);
        }
        __syncthreads();
    }

    // output routing (block-uniform)
    u16* Cw; int ldc, cb0;
    if (bn < split1)      { Cw = C0; ldc = ldc0; cb0 = bn; }
    else if (bn < split2) { Cw = C1; ldc = ldc1; cb0 = bn - split1; }
    else                  { Cw = C2; ldc = ldc2; cb0 = bn - split2; }

    // epilogue: C/D frag layout col = lane&15, row = (lane>>4)*4 + reg
    float bj0[4], bj1[4];
    float bj4[4][4];
    if constexpr (BIASK == 4) {
#pragma unroll
        for (int e = 0; e < 4; ++e)
#pragma unroll
            for (int j = 0; j < 4; ++j)
                bj4[e][j] = bias0[e * 256 + bn + wc * 64 + j * 16 + l15];
    } else {
#pragma unroll
        for (int j = 0; j < 4; ++j) {
            int col = bn + wc * 64 + j * 16 + l15;
            bj0[j] = bias0[col];
            if (BIASK == 3) bj1[j] = bias1[col];
        }
    }
#pragma unroll
    for (int i = 0; i < 4; ++i) {
        int row0 = bm + wr * 64 + i * 16 + l4 * 4;
#pragma unroll
        for (int r2 = 0; r2 < 4; ++r2) {
            int row = row0 + r2;
            if (row < N_NODES) {
#pragma unroll
                for (int j = 0; j < 4; ++j) {
                    int col = cb0 + wc * 64 + j * 16 + l15;
                    float o = acc[i][j][r2];
                    if constexpr (BIASK == 4) {
                        int bits = degmask[row];
#pragma unroll
                        for (int e = 0; e < 4; ++e)
                            o += ((bits >> e) & 1) ? bj4[e][j] : 0.f;
                    } else if constexpr (BIASK == 3) {
                        int bits = degmask[row] >> mshift;
                        o += ((bits & 1) ? bj0[j] : 0.f) + ((bits & 2) ? bj1[j] : 0.f);
                    } else {
                        o += bj0[j];
                    }
                    u16* cp = Cw + (size_t)row * ldc + col;
                    if (ACCUM) o += b2f(*cp);
                    *cp = f2b(o);
                }
            }
        }
    }
}

// ---------------------------------------------------------------------------
// fused GRU cell + LayerNorm: one WAVE per node, vectorized, shuffle-only.
// ---------------------------------------------------------------------------
template <int OUTM>
__global__ __launch_bounds__(256) void gru_ln_kernel(
    const u16* __restrict__ rz, const u16* __restrict__ nin,
    const u16* __restrict__ hn, const u16* __restrict__ hb,
    void* __restrict__ outv,
    const float* __restrict__ gamma, const float* __restrict__ beta)
{
    int w = threadIdx.x >> 6;
    int l = threadIdx.x & 63;
    int n = blockIdx.x * 4 + w;
    size_t b2 = (size_t)n * 512;
    size_t b1 = (size_t)n * D;

    u16 ra[4], za[4], na[4], ha[4], va[4];
    *reinterpret_cast<ushort4*>(ra) = *reinterpret_cast<const ushort4*>(rz + b2 + l * 4);
    *reinterpret_cast<ushort4*>(za) = *reinterpret_cast<const ushort4*>(rz + b2 + 256 + l * 4);
    *reinterpret_cast<ushort4*>(na) = *reinterpret_cast<const ushort4*>(nin + b1 + l * 4);
    *reinterpret_cast<ushort4*>(ha) = *reinterpret_cast<const ushort4*>(hn + b1 + l * 4);
    *reinterpret_cast<ushort4*>(va) = *reinterpret_cast<const ushort4*>(hb + b1 + l * 4);

    float hnew[4];
    float s1 = 0.f, s2 = 0.f;
#pragma unroll
    for (int c = 0; c < 4; ++c) {
        float r = 1.f / (1.f + __expf(-b2f(ra[c])));
        float z = 1.f / (1.f + __expf(-b2f(za[c])));
        float xn = b2f(na[c]) + r * b2f(ha[c]);
        float nn = 2.f / (1.f + __expf(-2.f * xn)) - 1.f;   // tanh
        hnew[c] = (1.f - z) * nn + z * b2f(va[c]);
        s1 += hnew[c];
        s2 += hnew[c] * hnew[c];
    }
#pragma unroll
    for (int o = 32; o > 0; o >>= 1) {
        s1 += __shfl_down(s1, o);
        s2 += __shfl_down(s2, o);
    }
    float sum = __shfl(s1, 0);
    float ssq = __shfl(s2, 0);
    float mu = sum * (1.f / D);
    float var = ssq * (1.f / D) - mu * mu;
    float rstd = rsqrtf(var + 1e-5f);

    float4 g = *reinterpret_cast<const float4*>(gamma + l * 4);
    float4 bt = *reinterpret_cast<const float4*>(beta + l * 4);
    float res[4];
    res[0] = (hnew[0] - mu) * rstd * g.x + bt.x;
    res[1] = (hnew[1] - mu) * rstd * g.y + bt.y;
    res[2] = (hnew[2] - mu) * rstd * g.z + bt.z;
    res[3] = (hnew[3] - mu) * rstd * g.w + bt.w;

    if (OUTM == 0) {
        ushort4 o;
        o.x = f2b(res[0]); o.y = f2b(res[1]); o.z = f2b(res[2]); o.w = f2b(res[3]);
        *reinterpret_cast<ushort4*>((u16*)outv + b1 + l * 4) = o;
    } else {
        *reinterpret_cast<float4*>((float*)outv + b1 + l * 4) =
            make_float4(res[0], res[1], res[2], res[3]);
    }
}

__global__ __launch_bounds__(256) void wsfail_kernel(float* __restrict__ out, float val, int n)
{
    int i = blockIdx.x * 256 + threadIdx.x;
    if (i < n) out[i] = val;
}

// ---------------------------------------------------------------------------
extern "C" void kernel_launch(void* const* d_in, const int* in_sizes, int n_in,
                              void* d_out, int out_size, void* d_ws, size_t ws_size,
                              hipStream_t stream)
{
    const float* x    = (const float*)d_in[0];
    const int* se[4] = {(const int*)d_in[1], (const int*)d_in[5],
                        (const int*)d_in[9], (const int*)d_in[13]};
    const int* de[4] = {(const int*)d_in[2], (const int*)d_in[6],
                        (const int*)d_in[10], (const int*)d_in[14]};
    const float* We[4] = {(const float*)d_in[3], (const float*)d_in[7],
                          (const float*)d_in[11], (const float*)d_in[15]};
    const float* be[4] = {(const float*)d_in[4], (const float*)d_in[8],
                          (const float*)d_in[12], (const float*)d_in[16]};
    const float* W_ih = (const float*)d_in[17];
    const float* W_hh = (const float*)d_in[18];
    const float* b_ih = (const float*)d_in[19];
    const float* b_hh = (const float*)d_in[20];
    const float* gamma = (const float*)d_in[21];
    const float* beta  = (const float*)d_in[22];
    float* outf = (float*)d_out;          // f32 [N,D], written at final step only

    const size_t SZ_H4 = (size_t)N_NODES * 1024 * 2;   // 102.4 MB
    const size_t SZ_H2 = (size_t)N_NODES * 512 * 2;    //  51.2 MB
    const size_t SZ_ND = (size_t)N_NODES * 256 * 2;    //  25.6 MB
    const size_t TAIL = 800016 + 3136 + 2400000 + 2400000 + 50000
                      + 1048576 + 524288 + 4096 + 4096;      // ~7.23 MB
    const size_t NEED_BIG   = SZ_H4 + 2 * SZ_ND + TAIL;      // ~160.8 MB
    const size_t NEED_SMALL = SZ_H2 + 3 * SZ_ND + TAIL;      // ~135.2 MB (proven fit)

    const bool big = (ws_size >= NEED_BIG);

    char* p = (char*)d_ws;
    u16 *Hm, *rzb, *ninb, *hnb, *aggb, *h_bf;
    if (big) {
        Hm   = (u16*)p; p += SZ_H4;                      // gather out [N,1024]
        rzb  = Hm;                                       // aliases (Hm dead after agg)
        ninb = (u16*)((char*)Hm + SZ_H2);
        hnb  = (u16*)((char*)Hm + SZ_H2 + SZ_ND);
        aggb = (u16*)p; p += SZ_ND;
        h_bf = (u16*)p; p += SZ_ND;
    } else {
        Hm   = (u16*)p; p += SZ_H2;                      // gather out [N,512]
        rzb  = Hm;
        aggb = (u16*)p; p += SZ_ND;
        hnb  = aggb;                                     // aggb dead before hn GEMM
        ninb = (u16*)p; p += SZ_ND;
        h_bf = (u16*)p; p += SZ_ND;
    }
    int* rowptr = (int*)p; p += 800016;                  // 4*(N+1)*4
    int* bsum   = (int*)p; p += 3136;
    u16* colb   = (u16*)p; p += 2400000;
    u16* rank   = (u16*)p; p += 2400000;
    unsigned char* degmask = (unsigned char*)p; p += 50000;
    u16* Bfull_b = (u16*)p; p += 1048576;                // 1024x512 bf16
    u16* Bcat_b  = (u16*)p; p += 524288;                 // 256x1024 bf16
    float* bfull = (float*)p; p += 4096;
    float* be4   = (float*)p; p += 4096;

    if (ws_size < (size_t)(p - (char*)d_ws)) {
        wsfail_kernel<<<(out_size + 255) / 256, 256, 0, stream>>>(
            outf, (float)(ws_size >> 20), out_size);
        return;
    }

    // ---- once per launch: weight pack + CSR build ----
    hipMemsetAsync(rowptr, 0, (size_t)4 * (N_NODES + 1) * 4, stream);
    prep_kernel<<<2048, 256, 0, stream>>>(
        We[0], We[1], We[2], We[3], be[0], be[1], be[2], be[3],
        W_ih, W_hh, b_ih, b_hh, Bfull_b, Bcat_b, bfull, be4);
    xcvt_kernel<<<N_NODES * D / 4 / 256, 256, 0, stream>>>(x, h_bf);
    cnt_kernel<<<(4 * E_EDGES + 255) / 256, 256, 0, stream>>>(
        de[0], de[1], de[2], de[3], rowptr, rank);
    scan1_kernel<<<dim3(SCHUNKS, 4), 256, 0, stream>>>(rowptr, bsum);
    scan2_kernel<<<4, 256, 0, stream>>>(bsum);
    scan3_kernel<<<dim3(SCHUNKS, 4), 256, 0, stream>>>(rowptr, bsum);
    fill_csr_kernel<<<(4 * E_EDGES + 255) / 256, 256, 0, stream>>>(
        se[0], de[0], se[1], de[1], se[2], de[2], se[3], de[3],
        rowptr, rank, colb);
    degmask_kernel<<<(N_NODES + 255) / 256, 256, 0, stream>>>(rowptr, degmask);

    const int BIG30 = 1 << 30;
    for (int step = 0; step < 3; ++step) {
        if (big) {
            // one gather over all 4 etypes -> Hmean4 [N,1024]
            gather_kernel<<<dim3(N_NODES / 2, 2), 256, 0, stream>>>(
                h_bf, rowptr, colb, Hm, -1, 1024);
            // agg = Hmean4 @ Bcat1024^T + 4-masked biases
            gemm_mfma<4, false><<<dim3(2, 391), 256, 0, stream>>>(
                Hm, 1024, nullptr, 0, Bcat_b, 1024,
                aggb, 256, nullptr, 0, nullptr, 0,
                BIG30, BIG30, 16, 16, be4, nullptr, degmask, 0);
            // fused rz|nin|hn: zones [0,512) dual / [512,768) agg / [768,1024) h
            gemm_mfma<1, false><<<dim3(8, 391), 256, 0, stream>>>(
                aggb, 256, h_bf, 256, Bfull_b, 512,
                rzb, 512, ninb, 256, hnb, 256,
                512, 768, 8, 4, bfull, nullptr, nullptr, 0);
        } else {
            for (int pair = 0; pair < 2; ++pair) {
                gather_kernel<<<dim3(N_NODES / 2, 1), 256, 0, stream>>>(
                    h_bf, rowptr, colb, Hm, pair, 512);
                if (pair == 0)
                    gemm_mfma<3, false><<<dim3(2, 391), 256, 0, stream>>>(
                        Hm, 512, nullptr, 0, Bcat_b + 512, 1024,
                        aggb, 256, nullptr, 0, nullptr, 0,
                        BIG30, BIG30, 8, 8, be4, be4 + 256, degmask, 0);
                else
                    gemm_mfma<3, true><<<dim3(2, 391), 256, 0, stream>>>(
                        Hm, 512, nullptr, 0, Bcat_b + 512, 1024,
                        aggb, 256, nullptr, 0, nullptr, 0,
                        BIG30, BIG30, 8, 8, be4 + 512, be4 + 768, degmask, 2);
                // NOTE: Bcat1024 col offset: pair0 cols 0-511 (e0,e1) at +0... see below
            }
            // fused rz+nin (no zone2; hn separate since hnb aliases aggb)
            gemm_mfma<1, false><<<dim3(6, 391), 256, 0, stream>>>(
                aggb, 256, h_bf, 256, Bfull_b, 512,
                rzb, 512, ninb, 256, nullptr, 0,
                512, BIG30, 8, 4, bfull, nullptr, nullptr, 0);
            // h_n = h @ WnH^T + b_hn  (zone2-only call; B rows 768.. of Bfull)
            gemm_mfma<1, false><<<dim3(2, 391), 256, 0, stream>>>(
                nullptr, 0, h_bf, 256, Bfull_b + (size_t)768 * 512, 512,
                nullptr, 0, nullptr, 0, hnb, 256,
                0, 0, 4, 4, bfull + 768, nullptr, nullptr, 0);
        }

        // steps 0,1 -> h_bf (bf16, in-place safe); step 2 -> d_out (f32)
        if (step < 2)
            gru_ln_kernel<0><<<N_NODES / 4, 256, 0, stream>>>(
                rzb, ninb, hnb, h_bf, h_bf, gamma, beta);
        else
            gru_ln_kernel<1><<<N_NODES / 4, 256, 0, stream>>>(
                rzb, ninb, hnb, h_bf, outf, gamma, beta);
    }
}

// Round 12
// 785.754 us; speedup vs baseline: 19.2000x; 1.0348x over previous
//
#include <hip/hip_runtime.h>
#include <hip/hip_bf16.h>
#include <cstddef>

#define N_NODES 50000
#define E_EDGES 300000
#define D 256
#define SCHUNKS 196           // ceil(50001/256)

typedef unsigned short u16;
typedef __attribute__((ext_vector_type(8))) short bf16x8;   // 8 bf16 = 4 VGPRs
typedef __attribute__((ext_vector_type(4))) float f32x4;

__device__ __forceinline__ float b2f(u16 u) {
    return __uint_as_float(((unsigned)u) << 16);
}
__device__ __forceinline__ u16 f2b(float f) {
    __hip_bfloat16 h = __float2bfloat16(f);
    return *reinterpret_cast<u16*>(&h);
}
__device__ __forceinline__ void async16(const u16* g, u16* l) {
    __builtin_amdgcn_global_load_lds(
        (const __attribute__((address_space(1))) void*)g,
        (__attribute__((address_space(3))) void*)l, 16, 0, 0);
}

// ---------------------------------------------------------------------------
// prep: pack weights to bf16 once.
//  Bfull[j][k] (1024x512):
//    k<256 : j<768 ? W_ih[j][k] : W_hh[j-256][k]     (rz + i_n + h_n rows)
//    k>=256: j<512 ? W_hh[j][k-256] : 0
//  Bcat1024[j][k] (256x1024) = W_{k>>8}[j][k&255]
//  bfull[1024] = j<512: b_ih+b_hh; 512-767: b_ih[j]; 768-1023: b_hh[j-256]
//  be4[e*256+k] = b_e[k]
// ---------------------------------------------------------------------------
__global__ __launch_bounds__(256) void prep_kernel(
    const float* __restrict__ W0, const float* __restrict__ W1,
    const float* __restrict__ W2, const float* __restrict__ W3,
    const float* __restrict__ b0, const float* __restrict__ b1,
    const float* __restrict__ b2, const float* __restrict__ b3,
    const float* __restrict__ W_ih, const float* __restrict__ W_hh,
    const float* __restrict__ b_ih, const float* __restrict__ b_hh,
    u16* __restrict__ Bfull_b, u16* __restrict__ Bcat_b,
    float* __restrict__ bfull, float* __restrict__ be4)
{
    int t = blockIdx.x * 256 + threadIdx.x;    // [0, 524288)
    {
        int j = t >> 9, k = t & 511;
        float v;
        if (k < 256) v = (j < 768) ? W_ih[j * 256 + k] : W_hh[(j - 256) * 256 + k];
        else         v = (j < 512) ? W_hh[j * 256 + (k - 256)] : 0.f;
        Bfull_b[t] = f2b(v);
    }
    if (t < 262144) {
        int j = t >> 10, k = t & 1023;
        int e = k >> 8, kk = k & 255;
        const float* W = (e == 0) ? W0 : (e == 1) ? W1 : (e == 2) ? W2 : W3;
        Bcat_b[t] = f2b(W[j * 256 + kk]);
    }
    if (t < 1024) {
        bfull[t] = (t < 512) ? b_ih[t] + b_hh[t]
                 : (t < 768) ? b_ih[t] : b_hh[t - 256];
        int e = t >> 8, k = t & 255;
        const float* b = (e == 0) ? b0 : (e == 1) ? b1 : (e == 2) ? b2 : b3;
        be4[t] = b[k];
    }
}

__global__ __launch_bounds__(256) void xcvt_kernel(
    const float* __restrict__ x, u16* __restrict__ hb)
{
    int t = blockIdx.x * 256 + threadIdx.x;      // 4-elem slot
    float4 v = *reinterpret_cast<const float4*>(x + (size_t)t * 4);
    ushort4 o;
    o.x = f2b(v.x); o.y = f2b(v.y); o.z = f2b(v.z); o.w = f2b(v.w);
    *reinterpret_cast<ushort4*>(hb + (size_t)t * 4) = o;
}

// ---------------------------------------------------------------------------
// CSR build, rank-based (one atomic pass):
//  cnt: counts at rp[e][dst+1], stores per-edge rank (old count).
//  scan: rp = inclusive scan -> beg(n)=rp[n], end(n)=rp[n+1].
//  fill: slot = rp[dst] + rank (no atomics); also emits degmask.
// ---------------------------------------------------------------------------
__global__ __launch_bounds__(256) void cnt_kernel(
    const int* __restrict__ d0, const int* __restrict__ d1,
    const int* __restrict__ d2, const int* __restrict__ d3,
    int* __restrict__ rowptr, u16* __restrict__ rank)
{
    int i = blockIdx.x * 256 + threadIdx.x;
    if (i >= 4 * E_EDGES) return;
    int e = i / E_EDGES;
    int k = i - e * E_EDGES;
    const int* dp = (e == 0) ? d0 : (e == 1) ? d1 : (e == 2) ? d2 : d3;
    rank[i] = (u16)atomicAdd(&rowptr[e * (N_NODES + 1) + dp[k] + 1], 1);
}

__global__ __launch_bounds__(256) void scan1_kernel(
    int* __restrict__ rowptr, int* __restrict__ bsum)
{
    int e = blockIdx.y;
    int blk = blockIdx.x;
    int t = threadIdx.x;
    int idx = blk * 256 + t;
    int* rp = rowptr + e * (N_NODES + 1);
    int v = (idx <= N_NODES) ? rp[idx] : 0;
    __shared__ int s[256];
    s[t] = v;
    __syncthreads();
    for (int o = 1; o < 256; o <<= 1) {
        int u = (t >= o) ? s[t - o] : 0;
        __syncthreads();
        s[t] += u;
        __syncthreads();
    }
    if (idx <= N_NODES) rp[idx] = s[t];
    if (t == 255) bsum[e * SCHUNKS + blk] = s[255];
}

__global__ __launch_bounds__(256) void scan2_kernel(int* __restrict__ bsum)
{
    int e = blockIdx.x;
    int t = threadIdx.x;
    int v = (t < SCHUNKS) ? bsum[e * SCHUNKS + t] : 0;
    __shared__ int s[256];
    s[t] = v;
    __syncthreads();
    for (int o = 1; o < 256; o <<= 1) {
        int u = (t >= o) ? s[t - o] : 0;
        __syncthreads();
        s[t] += u;
        __syncthreads();
    }
    if (t < SCHUNKS) bsum[e * SCHUNKS + t] = s[t];
}

__global__ __launch_bounds__(256) void scan3_kernel(
    int* __restrict__ rowptr, const int* __restrict__ bsum)
{
    int e = blockIdx.y;
    int blk = blockIdx.x;
    if (blk == 0) return;
    int idx = blk * 256 + threadIdx.x;
    if (idx > N_NODES) return;
    rowptr[e * (N_NODES + 1) + idx] += bsum[e * SCHUNKS + blk - 1];
}

__global__ __launch_bounds__(256) void fill_csr_kernel(
    const int* __restrict__ s0, const int* __restrict__ d0,
    const int* __restrict__ s1, const int* __restrict__ d1,
    const int* __restrict__ s2, const int* __restrict__ d2,
    const int* __restrict__ s3, const int* __restrict__ d3,
    const int* __restrict__ rowptr, const u16* __restrict__ rank,
    u16* __restrict__ colb, unsigned char* __restrict__ degmask)
{
    int i = blockIdx.x * 256 + threadIdx.x;
    if (i >= 4 * E_EDGES) return;
    int e = i / E_EDGES;
    int k = i - e * E_EDGES;
    const int* sp = (e == 0) ? s0 : (e == 1) ? s1 : (e == 2) ? s2 : s3;
    const int* dp = (e == 0) ? d0 : (e == 1) ? d1 : (e == 2) ? d2 : d3;
    int dst = dp[k];
    int slot = rowptr[e * (N_NODES + 1) + dst] + (int)rank[i];
    colb[(size_t)e * E_EDGES + slot] = (u16)sp[k];
    if (i < N_NODES) {
        int m = 0;
#pragma unroll
        for (int ee = 0; ee < 4; ++ee) {
            const int* rp = rowptr + ee * (N_NODES + 1);
            if (rp[i + 1] > rp[i]) m |= (1 << ee);
        }
        degmask[i] = (unsigned char)m;
    }
}

// ---------------------------------------------------------------------------
// gather: Hmean4[n][e*256+c] = mean over in-edges(e) of hb[src][c]
// grid (N/2, 2); wave = etype-slot; 4-deep ILP.
// ---------------------------------------------------------------------------
__global__ __launch_bounds__(256) void gather_kernel(
    const u16* __restrict__ hb, const int* __restrict__ rowptr,
    const u16* __restrict__ colb, u16* __restrict__ out)
{
    int p = blockIdx.y;
    int n = blockIdx.x * 2 + (threadIdx.x >> 7);
    int el = (threadIdx.x >> 6) & 1;
    int lane = threadIdx.x & 63;
    int e = p * 2 + el;
    const int* rp = rowptr + e * (N_NODES + 1);
    int beg = rp[n], end = rp[n + 1];
    const u16* cb = colb + (size_t)e * E_EDGES;

    float4 a0 = make_float4(0.f, 0.f, 0.f, 0.f);
    float4 a1 = a0, a2 = a0, a3 = a0;
    int j = beg;
    for (; j + 4 <= end; j += 4) {
        int s0 = cb[j], s1 = cb[j + 1], s2 = cb[j + 2], s3 = cb[j + 3];
        ushort4 u0 = *reinterpret_cast<const ushort4*>(hb + (size_t)s0 * D + lane * 4);
        ushort4 u1 = *reinterpret_cast<const ushort4*>(hb + (size_t)s1 * D + lane * 4);
        ushort4 u2 = *reinterpret_cast<const ushort4*>(hb + (size_t)s2 * D + lane * 4);
        ushort4 u3 = *reinterpret_cast<const ushort4*>(hb + (size_t)s3 * D + lane * 4);
        a0.x += b2f(u0.x); a0.y += b2f(u0.y); a0.z += b2f(u0.z); a0.w += b2f(u0.w);
        a1.x += b2f(u1.x); a1.y += b2f(u1.y); a1.z += b2f(u1.z); a1.w += b2f(u1.w);
        a2.x += b2f(u2.x); a2.y += b2f(u2.y); a2.z += b2f(u2.z); a2.w += b2f(u2.w);
        a3.x += b2f(u3.x); a3.y += b2f(u3.y); a3.z += b2f(u3.z); a3.w += b2f(u3.w);
    }
    for (; j < end; ++j) {
        int s0 = cb[j];
        ushort4 u0 = *reinterpret_cast<const ushort4*>(hb + (size_t)s0 * D + lane * 4);
        a0.x += b2f(u0.x); a0.y += b2f(u0.y); a0.z += b2f(u0.z); a0.w += b2f(u0.w);
    }
    float ax = (a0.x + a1.x) + (a2.x + a3.x);
    float ay = (a0.y + a1.y) + (a2.y + a3.y);
    float az = (a0.z + a1.z) + (a2.z + a3.z);
    float aw = (a0.w + a1.w) + (a2.w + a3.w);
    float s = (end > beg) ? 1.f / (float)(end - beg) : 0.f;
    ushort4 o;
    o.x = f2b(ax * s); o.y = f2b(ay * s); o.z = f2b(az * s); o.w = f2b(aw * s);
    *reinterpret_cast<ushort4*>(out + (size_t)n * 1024 + e * 256 + lane * 4) = o;
}

// ---------------------------------------------------------------------------
// MFMA GEMM, BM=128 x BN=256 tile, BK=64, 512 threads = 8 waves (2M x 4N,
// 64x64 per wave). XOR-swizzled LDS, global_load_lds staging, bijective XCD
// block swizzle. 3 output zones by col-block (bn multiples of 256):
//   bn < split1          : nkt0 k-tiles, kt<KS from A0 else A1   -> C0
//   split1 <= bn < split2: KS  k-tiles, all from A0              -> C1
//   bn >= split2         : KS  k-tiles, all from A1              -> C2
// A rows clamped to N-1; C rows guarded.
// BIASK 1: bias0[global col]. 4: 4-mask bias0[e*256+col] via degmask bits.
// ---------------------------------------------------------------------------
template <int BIASK>
__global__ __launch_bounds__(512, 4) void gemm_mfma(
    const u16* __restrict__ A0, int lda0,
    const u16* __restrict__ A1, int lda1,
    const u16* __restrict__ Bw, int ldb,
    u16* __restrict__ C0, int ldc0, u16* __restrict__ C1, int ldc1,
    u16* __restrict__ C2, int ldc2,
    int split1, int split2, int nkt0, int KS,
    const float* __restrict__ bias0, const unsigned char* __restrict__ degmask)
{
    __shared__ u16 As[8192];     // 128 x 64 bf16 (16 KB)
    __shared__ u16 Bs2[16384];   // 256 x 64 bf16 (32 KB)

    const int gx = gridDim.x;
    const int nwg = gx * gridDim.y;
    const int lin = blockIdx.y * gx + blockIdx.x;
    const int q = nwg >> 3, r = nwg & 7;
    const int xcd = lin & 7, pos = lin >> 3;
    const int wg = (xcd < r) ? xcd * (q + 1) + pos
                             : r * (q + 1) + (xcd - r) * q + pos;
    const int by = wg / gx;
    const int bx = wg - by * gx;
    const int bm = by * 128;
    const int bn = bx * 256;

    const int tid = threadIdx.x;
    const int lane = tid & 63;
    const int wid = tid >> 6;          // 0..7
    const int wr = wid >> 2;           // 0..1 (row half)
    const int wc = wid & 3;            // 0..3 (col quarter)
    const int l15 = lane & 15;
    const int l4 = lane >> 4;

    // staging slots: A 1024 slots (2/wave-pass), B 2048 slots (4/wave-pass)
    int arow[2], achk[2];
#pragma unroll
    for (int ps = 0; ps < 2; ++ps) {
        int s = wid * 128 + ps * 64 + lane;
        arow[ps] = s >> 3;
        achk[ps] = (s & 7) ^ (arow[ps] & 7);
    }
    int brow[4], bchk[4];
#pragma unroll
    for (int ps = 0; ps < 4; ++ps) {
        int s = wid * 256 + ps * 64 + lane;
        brow[ps] = s >> 3;
        bchk[ps] = (s & 7) ^ (brow[ps] & 7);
    }

    f32x4 acc[4][4];
#pragma unroll
    for (int i = 0; i < 4; ++i)
#pragma unroll
        for (int j = 0; j < 4; ++j)
            acc[i][j] = (f32x4){0.f, 0.f, 0.f, 0.f};

    int nkt, ksel;
    if (bn < split1)      { nkt = nkt0; ksel = KS; }
    else if (bn < split2) { nkt = KS;   ksel = KS; }
    else                  { nkt = KS;   ksel = 0;  }

    for (int kt = 0; kt < nkt; ++kt) {
        const u16* Ab; int lda;
        if (kt < ksel) { Ab = A0 + (size_t)kt * 64;          lda = lda0; }
        else           { Ab = A1 + (size_t)(kt - ksel) * 64; lda = lda1; }
#pragma unroll
        for (int ps = 0; ps < 2; ++ps) {
            int rrow = bm + arow[ps];
            if (rrow > N_NODES - 1) rrow = N_NODES - 1;
            async16(Ab + (size_t)rrow * lda + achk[ps] * 8,
                    &As[(wid * 128 + ps * 64) * 8]);
        }
#pragma unroll
        for (int ps = 0; ps < 4; ++ps)
            async16(Bw + (size_t)(bn + brow[ps]) * ldb + kt * 64 + bchk[ps] * 8,
                    &Bs2[(wid * 256 + ps * 64) * 8]);
        __syncthreads();

#pragma unroll
        for (int kk = 0; kk < 2; ++kk) {
            bf16x8 a[4], b[4];
#pragma unroll
            for (int i = 0; i < 4; ++i) {
                int ar = wr * 64 + i * 16 + l15;
                a[i] = *reinterpret_cast<const bf16x8*>(
                    &As[ar * 64 + (((kk * 4 + l4) ^ (ar & 7)) << 3)]);
                int bc = wc * 64 + i * 16 + l15;
                b[i] = *reinterpret_cast<const bf16x8*>(
                    &Bs2[bc * 64 + (((kk * 4 + l4) ^ (bc & 7)) << 3)]);
            }
#pragma unroll
            for (int i = 0; i < 4; ++i)
#pragma unroll
                for (int j = 0; j < 4; ++j)
                    acc[i][j] = __builtin_amdgcn_mfma_f32_16x16x32_bf16(
                        a[i], b[j], acc[i][j], 0, 0, 0);
        }
        __syncthreads();
    }

    // output routing (block-uniform)
    u16* Cw; int ldc, cb0;
    if (bn < split1)      { Cw = C0; ldc = ldc0; cb0 = bn; }
    else if (bn < split2) { Cw = C1; ldc = ldc1; cb0 = bn - split1; }
    else                  { Cw = C2; ldc = ldc2; cb0 = bn - split2; }

    // epilogue: C/D frag layout col = lane&15, row = (lane>>4)*4 + reg
    float bj0[4];
    float bj4[4][4];
    if constexpr (BIASK == 4) {
#pragma unroll
        for (int e = 0; e < 4; ++e)
#pragma unroll
            for (int j = 0; j < 4; ++j)
                bj4[e][j] = bias0[e * 256 + bn + wc * 64 + j * 16 + l15];
    } else {
#pragma unroll
        for (int j = 0; j < 4; ++j)
            bj0[j] = bias0[bn + wc * 64 + j * 16 + l15];
    }
#pragma unroll
    for (int i = 0; i < 4; ++i) {
        int row0 = bm + wr * 64 + i * 16 + l4 * 4;
#pragma unroll
        for (int r2 = 0; r2 < 4; ++r2) {
            int row = row0 + r2;
            if (row < N_NODES) {
#pragma unroll
                for (int j = 0; j < 4; ++j) {
                    int col = cb0 + wc * 64 + j * 16 + l15;
                    float o = acc[i][j][r2];
                    if constexpr (BIASK == 4) {
                        int bits = degmask[row];
#pragma unroll
                        for (int e = 0; e < 4; ++e)
                            o += ((bits >> e) & 1) ? bj4[e][j] : 0.f;
                    } else {
                        o += bj0[j];
                    }
                    Cw[(size_t)row * ldc + col] = f2b(o);
                }
            }
        }
    }
}

// ---------------------------------------------------------------------------
// fused GRU cell + LayerNorm: one WAVE per node, vectorized, shuffle-only.
// ---------------------------------------------------------------------------
template <int OUTM>
__global__ __launch_bounds__(256) void gru_ln_kernel(
    const u16* __restrict__ rz, const u16* __restrict__ nin,
    const u16* __restrict__ hn, const u16* __restrict__ hb,
    void* __restrict__ outv,
    const float* __restrict__ gamma, const float* __restrict__ beta)
{
    int w = threadIdx.x >> 6;
    int l = threadIdx.x & 63;
    int n = blockIdx.x * 4 + w;
    size_t b2 = (size_t)n * 512;
    size_t b1 = (size_t)n * D;

    u16 ra[4], za[4], na[4], ha[4], va[4];
    *reinterpret_cast<ushort4*>(ra) = *reinterpret_cast<const ushort4*>(rz + b2 + l * 4);
    *reinterpret_cast<ushort4*>(za) = *reinterpret_cast<const ushort4*>(rz + b2 + 256 + l * 4);
    *reinterpret_cast<ushort4*>(na) = *reinterpret_cast<const ushort4*>(nin + b1 + l * 4);
    *reinterpret_cast<ushort4*>(ha) = *reinterpret_cast<const ushort4*>(hn + b1 + l * 4);
    *reinterpret_cast<ushort4*>(va) = *reinterpret_cast<const ushort4*>(hb + b1 + l * 4);

    float hnew[4];
    float s1 = 0.f, s2 = 0.f;
#pragma unroll
    for (int c = 0; c < 4; ++c) {
        float r = 1.f / (1.f + __expf(-b2f(ra[c])));
        float z = 1.f / (1.f + __expf(-b2f(za[c])));
        float xn = b2f(na[c]) + r * b2f(ha[c]);
        float nn = 2.f / (1.f + __expf(-2.f * xn)) - 1.f;   // tanh
        hnew[c] = (1.f - z) * nn + z * b2f(va[c]);
        s1 += hnew[c];
        s2 += hnew[c] * hnew[c];
    }
#pragma unroll
    for (int o = 32; o > 0; o >>= 1) {
        s1 += __shfl_down(s1, o);
        s2 += __shfl_down(s2, o);
    }
    float sum = __shfl(s1, 0);
    float ssq = __shfl(s2, 0);
    float mu = sum * (1.f / D);
    float var = ssq * (1.f / D) - mu * mu;
    float rstd = rsqrtf(var + 1e-5f);

    float4 g = *reinterpret_cast<const float4*>(gamma + l * 4);
    float4 bt = *reinterpret_cast<const float4*>(beta + l * 4);
    float res[4];
    res[0] = (hnew[0] - mu) * rstd * g.x + bt.x;
    res[1] = (hnew[1] - mu) * rstd * g.y + bt.y;
    res[2] = (hnew[2] - mu) * rstd * g.z + bt.z;
    res[3] = (hnew[3] - mu) * rstd * g.w + bt.w;

    if (OUTM == 0) {
        ushort4 o;
        o.x = f2b(res[0]); o.y = f2b(res[1]); o.z = f2b(res[2]); o.w = f2b(res[3]);
        *reinterpret_cast<ushort4*>((u16*)outv + b1 + l * 4) = o;
    } else {
        *reinterpret_cast<float4*>((float*)outv + b1 + l * 4) =
            make_float4(res[0], res[1], res[2], res[3]);
    }
}

__global__ __launch_bounds__(256) void wsfail_kernel(float* __restrict__ out, float val, int n)
{
    int i = blockIdx.x * 256 + threadIdx.x;
    if (i < n) out[i] = val;
}

// ---------------------------------------------------------------------------
extern "C" void kernel_launch(void* const* d_in, const int* in_sizes, int n_in,
                              void* d_out, int out_size, void* d_ws, size_t ws_size,
                              hipStream_t stream)
{
    const float* x    = (const float*)d_in[0];
    const int* se[4] = {(const int*)d_in[1], (const int*)d_in[5],
                        (const int*)d_in[9], (const int*)d_in[13]};
    const int* de[4] = {(const int*)d_in[2], (const int*)d_in[6],
                        (const int*)d_in[10], (const int*)d_in[14]};
    const float* We[4] = {(const float*)d_in[3], (const float*)d_in[7],
                          (const float*)d_in[11], (const float*)d_in[15]};
    const float* be[4] = {(const float*)d_in[4], (const float*)d_in[8],
                          (const float*)d_in[12], (const float*)d_in[16]};
    const float* W_ih = (const float*)d_in[17];
    const float* W_hh = (const float*)d_in[18];
    const float* b_ih = (const float*)d_in[19];
    const float* b_hh = (const float*)d_in[20];
    const float* gamma = (const float*)d_in[21];
    const float* beta  = (const float*)d_in[22];
    float* outf = (float*)d_out;          // f32 [N,D], written at final step only

    const size_t SZ_H4 = (size_t)N_NODES * 1024 * 2;   // 102.4 MB
    const size_t SZ_H2 = (size_t)N_NODES * 512 * 2;    //  51.2 MB
    const size_t SZ_ND = (size_t)N_NODES * 256 * 2;    //  25.6 MB

    char* p = (char*)d_ws;
    u16* Hm   = (u16*)p; p += SZ_H4;                   // gather out [N,1024]
    u16* rzb  = Hm;                                    // aliases (Hm dead after agg)
    u16* ninb = (u16*)((char*)Hm + SZ_H2);
    u16* hnb  = (u16*)((char*)Hm + SZ_H2 + SZ_ND);
    u16* aggb = (u16*)p; p += SZ_ND;
    u16* h_bf = (u16*)p; p += SZ_ND;
    int* rowptr = (int*)p; p += 800016;                // 4*(N+1)*4
    int* bsum   = (int*)p; p += 3136;
    u16* colb   = (u16*)p; p += 2400000;
    u16* rank   = (u16*)p; p += 2400000;
    unsigned char* degmask = (unsigned char*)p; p += 50000;
    u16* Bfull_b = (u16*)p; p += 1048576;              // 1024x512 bf16
    u16* Bcat_b  = (u16*)p; p += 524288;               // 256x1024 bf16
    float* bfull = (float*)p; p += 4096;
    float* be4   = (float*)p; p += 4096;

    if (ws_size < (size_t)(p - (char*)d_ws)) {
        wsfail_kernel<<<(out_size + 255) / 256, 256, 0, stream>>>(
            outf, (float)(ws_size >> 20), out_size);
        return;
    }

    // ---- once per launch: weight pack + CSR build ----
    hipMemsetAsync(rowptr, 0, (size_t)4 * (N_NODES + 1) * 4, stream);
    prep_kernel<<<2048, 256, 0, stream>>>(
        We[0], We[1], We[2], We[3], be[0], be[1], be[2], be[3],
        W_ih, W_hh, b_ih, b_hh, Bfull_b, Bcat_b, bfull, be4);
    xcvt_kernel<<<N_NODES * D / 4 / 256, 256, 0, stream>>>(x, h_bf);
    cnt_kernel<<<(4 * E_EDGES + 255) / 256, 256, 0, stream>>>(
        de[0], de[1], de[2], de[3], rowptr, rank);
    scan1_kernel<<<dim3(SCHUNKS, 4), 256, 0, stream>>>(rowptr, bsum);
    scan2_kernel<<<4, 256, 0, stream>>>(bsum);
    scan3_kernel<<<dim3(SCHUNKS, 4), 256, 0, stream>>>(rowptr, bsum);
    fill_csr_kernel<<<(4 * E_EDGES + 255) / 256, 256, 0, stream>>>(
        se[0], de[0], se[1], de[1], se[2], de[2], se[3], de[3],
        rowptr, rank, colb, degmask);

    const int BIG30 = 1 << 30;
    for (int step = 0; step < 3; ++step) {
        // one gather over all 4 etypes -> Hmean4 [N,1024]
        gather_kernel<<<dim3(N_NODES / 2, 2), 256, 0, stream>>>(
            h_bf, rowptr, colb, Hm);
        // agg = Hmean4 @ Bcat1024^T + 4-masked biases   (BN=256: 1 col-block)
        gemm_mfma<4><<<dim3(1, 391), 512, 0, stream>>>(
            Hm, 1024, nullptr, 0, Bcat_b, 1024,
            aggb, 256, nullptr, 0, nullptr, 0,
            BIG30, BIG30, 16, 16, be4, degmask);
        // fused rz|nin|hn: zones [0,512) dual / [512,768) agg / [768,1024) h
        gemm_mfma<1><<<dim3(4, 391), 512, 0, stream>>>(
            aggb, 256, h_bf, 256, Bfull_b, 512,
            rzb, 512, ninb, 256, hnb, 256,
            512, 768, 8, 4, bfull, nullptr);

        // steps 0,1 -> h_bf (bf16, in-place safe); step 2 -> d_out (f32)
        if (step < 2)
            gru_ln_kernel<0><<<N_NODES / 4, 256, 0, stream>>>(
                rzb, ninb, hnb, h_bf, h_bf, gamma, beta);
        else
            gru_ln_kernel<1><<<N_NODES / 4, 256, 0, stream>>>(
                rzb, ninb, hnb, h_bf, outf, gamma, beta);
    }
}